// Round 9
// baseline (726.432 us; speedup 1.0000x reference)
//
#include <hip/hip_runtime.h>
#include <hip/hip_bf16.h>

#define NN 50000
#define NE 800000
#define FD 80
#define NGR 1024
#define NF 9

// bucketed CSR sort (atomic-free counting sort)
#define BSH 6
#define NBUCK ((NN + 63) >> 6)     // 782 node-buckets of 64
#define CSH 10
#define NCH ((NE + 1023) >> 10)    // 782 edge-chunks of 1024
#define BCAP 2048

using bf16 = __hip_bfloat16;
typedef __attribute__((ext_vector_type(8))) short bf16x8;
typedef __attribute__((ext_vector_type(4))) float f32x4;

static __device__ __forceinline__ float b2f(bf16 v){ return __bfloat162float(v); }
static __device__ __forceinline__ bf16 f2b(float v){ return __float2bfloat16(v); }
static __device__ __forceinline__ float rdw(const void* p, int i, int fl){
  return fl ? ((const float*)p)[i] : b2f(((const bf16*)p)[i]);
}
static __device__ __forceinline__ unsigned pk(float a, float b){
  bf16 x = f2b(a), y = f2b(b);
  return (unsigned)*(unsigned short*)&x | ((unsigned)*(unsigned short*)&y << 16);
}
// 8B-granule LDS access (strides are 8B- but not 16B-aligned)
static __device__ __forceinline__ bf16x8 ldsld8(const short* p){
  union { bf16x8 v; uint2 u[2]; } r;
  r.u[0] = *(const uint2*)(p);
  r.u[1] = *(const uint2*)(p + 4);
  return r.v;
}
static __device__ __forceinline__ void ldsst16(short* p, uint4 v){
  *(uint2*)(p)     = make_uint2(v.x, v.y);
  *(uint2*)(p + 4) = make_uint2(v.z, v.w);
}

// ------------------------------------------------------------------ utility
__global__ void k_zero(int* __restrict__ p, int n){
  int t = blockIdx.x*256 + threadIdx.x;
  if (t < n) p[t] = 0;
}

__global__ void k_probe(const void* __restrict__ emb, int* __restrict__ flag){
  int t = blockIdx.x*256 + threadIdx.x;
  float v = b2f(((const bf16*)emb)[t]);
  if (!(fabsf(v) < 1e4f)) atomicOr(flag, 1);
}

// ------------------------------------------------------------------ fused weight prep
__global__ __launch_bounds__(256) void k_prep_all(
    const void* __restrict__ preW, const void* __restrict__ preb,
    const void* __restrict__ postW, const void* __restrict__ postb,
    const void* __restrict__ linW, const void* __restrict__ linb,
    const void* __restrict__ bng, const void* __restrict__ bnb,
    const void* __restrict__ bnm, const void* __restrict__ bnv,
    const int* __restrict__ flag,
    bf16* __restrict__ pwb, bf16* __restrict__ Btl, bf16* __restrict__ Bt1,
    float* __restrict__ bias1, float* __restrict__ bias2)
{
  int fl = flag[0];
  int b = blockIdx.x;
  if (b < 1300){
    int t = b*256 + threadIdx.x;
    pwb[t] = f2b(rdw(postW, t, fl));
  } else if (b < 1420){
    int t = (b - 1300)*256 + threadIdx.x;
    int j = t % 96, c = (t/96) % 80, i = t/(96*80);
    float v = 0.f;
    if (j < 80){
      float gs = rdw(bng, i*80 + c, fl) * rsqrtf(rdw(bnv, i*80 + c, fl) + 1e-5f);
      v = rdw(linW, i*6400 + j*80 + c, fl) * gs;
    }
    Btl[t] = f2b(v);
  } else if (b < 1660){
    int t = (b - 1420)*256 + threadIdx.x;
    int k = t % 96, c = (t/96) % 160, i = t/(96*160);
    float v = 0.f;
    if (k < 80)
      v = (c < 80) ? rdw(preW, (i*160 + k)*80 + c, fl)
                   : rdw(preW, (i*160 + 80 + k)*80 + (c - 80), fl);
    Bt1[t] = f2b(v);
    if (k == 0) bias1[i*160 + c] = (c < 80) ? rdw(preb, i*80 + c, fl) : 0.f;
  } else {
    int t = (b - 1660)*256 + threadIdx.x;
    if (t >= 4*80) return;
    int i = t / 80, f = t - i*80;
    float s = 0.f;
    for (int j = 0; j < 80; j++)
      s += rdw(postb, i*80 + j, fl) * rdw(linW, (i*80 + j)*80 + f, fl);
    s += rdw(linb, t, fl);
    float gs = rdw(bng, t, fl) * rsqrtf(rdw(bnv, t, fl) + 1e-5f);
    bias2[t] = (s - rdw(bnm, t, fl)) * gs + rdw(bnb, t, fl);
  }
}

// Bt2[i][c][k] (c<240 cols, 416-k) from Wf (f32 [i][1040][80]).
__global__ void k_prep_Bt2(const float* __restrict__ Wf, bf16* __restrict__ Bt2){
  int t = blockIdx.x*256 + threadIdx.x;
  if (t >= 4*240*416) return;
  int k = t % 416;
  int c = (t/416) % 240;
  int i = t/(416*240);
  float v = 0.f;
  if (k < 400){
    int blk = c/80, f = c - blk*80;
    if (blk == 0) v = Wf[(i*1040 + k)*80 + f];
    else if (k >= 80){
      int row = (blk == 1 ? 400 : 720) + (k - 80);
      v = Wf[(i*1040 + row)*80 + f];
    }
  }
  Bt2[t] = f2b(v);
}

// ------------------------------------------------------------------ graph prep
__global__ void k_atom(const int* __restrict__ x, const void* __restrict__ emb,
                       const int* __restrict__ flag, float* __restrict__ h){
  int fl = flag[0];
  int gid = blockIdx.x*256 + threadIdx.x;
  if (gid >= NN*FD) return;
  int n = gid / FD, f = gid - n*FD;
  float s = 0.f;
  #pragma unroll
  for (int c = 0; c < NF; c++){
    int row = x[n*NF + c];
    s += rdw(emb, (c*119 + row)*FD + f, fl);
  }
  h[gid] = s;
}

// ---- atomic-free CSR build: hist -> cscan -> bscan -> place -> csr ----

// Per-chunk bucket histogram (coalesced matrix write).
__global__ __launch_bounds__(256) void k_hist(const int* __restrict__ ei,
                                              int* __restrict__ chunkcnt){
  __shared__ int hist[NBUCK];
  int c = blockIdx.x, t = threadIdx.x;
  for (int i = t; i < NBUCK; i += 256) hist[i] = 0;
  __syncthreads();
  #pragma unroll
  for (int j = 0; j < 4; j++){
    int e = (c << CSH) + j*256 + t;
    if (e < NE) atomicAdd(&hist[ei[NE + e] >> BSH], 1);
  }
  __syncthreads();
  for (int i = t; i < NBUCK; i += 256) chunkcnt[c*NBUCK + i] = hist[i];
}

// Per-bucket exclusive scan over chunks (in-place) + bucket totals.
__global__ __launch_bounds__(256) void k_cscan(int* __restrict__ chunkcnt,
                                               int* __restrict__ btotal){
  __shared__ int buf[256];
  int b = blockIdx.x, t = threadIdx.x;
  int v[4]; int s = 0;
  #pragma unroll
  for (int j = 0; j < 4; j++){
    int c = t*4 + j;
    v[j] = (c < NCH) ? chunkcnt[c*NBUCK + b] : 0;
    s += v[j];
  }
  buf[t] = s;
  __syncthreads();
  for (int off = 1; off < 256; off <<= 1){
    int xv = (t >= off) ? buf[t - off] : 0;
    __syncthreads();
    buf[t] += xv;
    __syncthreads();
  }
  int excl = buf[t] - s;
  #pragma unroll
  for (int j = 0; j < 4; j++){
    int c = t*4 + j;
    if (c < NCH){ chunkcnt[c*NBUCK + b] = excl; excl += v[j]; }
  }
  if (t == 255) btotal[b] = buf[255];
}

// Exclusive scan of bucket totals -> bucket base offsets (bbase[NBUCK] = NE).
__global__ __launch_bounds__(256) void k_bscan(const int* __restrict__ btotal,
                                               int* __restrict__ bbase){
  __shared__ int buf[256];
  int t = threadIdx.x;
  int v[4]; int s = 0;
  #pragma unroll
  for (int j = 0; j < 4; j++){
    int c = t*4 + j;
    v[j] = (c < NBUCK) ? btotal[c] : 0;
    s += v[j];
  }
  buf[t] = s;
  __syncthreads();
  for (int off = 1; off < 256; off <<= 1){
    int xv = (t >= off) ? buf[t - off] : 0;
    __syncthreads();
    buf[t] += xv;
    __syncthreads();
  }
  int excl = buf[t] - s;
  #pragma unroll
  for (int j = 0; j < 4; j++){
    int c = t*4 + j;
    if (c < NBUCK){ bbase[c] = excl; excl += v[j]; }
  }
  if (t == 255) bbase[NBUCK] = buf[255];
}

// Place each edge into its bucket's staging range; rank via LDS atomics.
__global__ __launch_bounds__(256) void k_place(const int* __restrict__ ei,
                        const int* __restrict__ chunkcnt, const int* __restrict__ bbase,
                        int* __restrict__ staging){
  __shared__ int basep[NBUCK];
  __shared__ int cur[NBUCK];
  int c = blockIdx.x, t = threadIdx.x;
  for (int i = t; i < NBUCK; i += 256){
    basep[i] = chunkcnt[c*NBUCK + i] + bbase[i];
    cur[i] = 0;
  }
  __syncthreads();
  #pragma unroll
  for (int j = 0; j < 4; j++){
    int e = (c << CSH) + j*256 + t;
    if (e < NE){
      int d = ei[NE + e], s = ei[e];
      int b = d >> BSH;
      int r = atomicAdd(&cur[b], 1);
      staging[basep[b] + r] = (s << BSH) | (d & 63);
    }
  }
}

// Fused per-bucket finalize: node counts -> rowptr/scf/invf + counting sort
// into colidx (sequential reads, coalesced writes).
__global__ __launch_bounds__(256) void k_csr(const int* __restrict__ staging,
                        const int* __restrict__ bbase, const void* __restrict__ avgp,
                        const int* __restrict__ flag, int* __restrict__ rowptr,
                        float* __restrict__ scf, float* __restrict__ invf,
                        int* __restrict__ colidx){
  __shared__ int lcnt[64], lrp[64], lcur[64];
  __shared__ int colbuf[BCAP];
  int b = blockIdx.x, t = threadIdx.x;
  int base = bbase[b];
  int cnt  = bbase[b+1] - base;
  if (t < 64){ lcnt[t] = 0; lcur[t] = 0; }
  __syncthreads();
  for (int i = t; i < cnt; i += 256)
    atomicAdd(&lcnt[staging[base + i] & 63], 1);
  __syncthreads();
  if (t < 64) lrp[t] = lcnt[t];
  __syncthreads();
  for (int off = 1; off < 64; off <<= 1){
    int xv = (t < 64 && t >= off) ? lrp[t - off] : 0;
    __syncthreads();
    if (t < 64) lrp[t] += xv;
    __syncthreads();
  }
  int n0 = b << BSH;
  if (t < 64){
    int ex = lrp[t] - lcnt[t];
    lrp[t] = ex;
    int n = n0 + t;
    if (n < NN){
      rowptr[n] = base + ex;
      float degc = (float)(lcnt[t] > 0 ? lcnt[t] : 1);
      float logd = logf(degc + 1.f);
      float avg = rdw(avgp, 0, flag[0]);
      scf[n] = logd / avg;
      invf[n] = avg / logd;
    }
  }
  if (b == 0 && t == 0) rowptr[NN] = NE;
  __syncthreads();
  if (cnt <= BCAP){
    for (int i = t; i < cnt; i += 256){
      int v = staging[base + i];
      int l = v & 63;
      int pos = lrp[l] + atomicAdd(&lcur[l], 1);
      colbuf[pos] = v >> BSH;
    }
    __syncthreads();
    for (int i = t; i < cnt; i += 256)
      colidx[base + i] = colbuf[i];
  } else {
    for (int i = t; i < cnt; i += 256){
      int v = staging[base + i];
      int l = v & 63;
      int pos = lrp[l] + atomicAdd(&lcur[l], 1);
      colidx[base + pos] = v >> BSH;
    }
  }
}

// ------------------------------------------------------------------ MFMA GEMM (r4 structure, best measured)
// 64-row x 256-col block tile, 4 waves. Full A-panel staged to LDS up-front,
// K-loop streams B via reg->LDS with prefetch. Used for Wf (OUTMODE1) and
// layer-0 GEMM1 (OUTMODE2).
template<int AF32, int OUTMODE, int K_, int AST>
__global__ __launch_bounds__(256) void k_mgemm(
    const void* __restrict__ A1p, int s1, int KA,
    const bf16* __restrict__ A2, int s2, int KB,
    const bf16* __restrict__ Btp, int Bts, int Ncols,
    const float* __restrict__ bias,
    void* __restrict__ Cbase, void* __restrict__ Cp2, int Cstride, int M,
    int lA1b, int lBtb, int lCb)
{
  const void* A1 = (const char*)A1p + (size_t)blockIdx.z*lA1b;
  const bf16* Bt = (const bf16*)((const char*)Btp + (size_t)blockIdx.z*lBtb);
  void* Cp = (char*)Cbase + (size_t)blockIdx.z*lCb;

  constexpr int NKT = K_ / 32;
  __shared__ short As[64*AST];
  __shared__ short Bs[256*44];

  const int tid = threadIdx.x;
  const int row0 = blockIdx.x * 64;
  const int wave = tid >> 6, lane = tid & 63;
  const int wc = wave * 64;
  const int m16 = lane & 15, q = lane >> 4;

  const int ra = tid >> 2, ka = (tid & 3) * 8;
  const int cb = tid >> 2, kb = (tid & 3) * 8;

  f32x4 acc[4][4] = {};
  uint4 pb[4];

#define LOADB(k0_) { int kgb = (k0_) + kb;                                     \
    _Pragma("unroll")                                                          \
    for (int j = 0; j < 4; j++){                                               \
      int col = cb + j*64;                                                     \
      pb[j].x = pb[j].y = pb[j].z = pb[j].w = 0u;                              \
      if (col < Ncols) pb[j] = *(const uint4*)(Bt + col*Bts + kgb);            \
    } }

  LOADB(0);

  {
    const int grow = row0 + ra;
    uint4 tA[NKT];
    #pragma unroll
    for (int c = 0; c < NKT; c++){
      int kg = c*32 + ka;
      uint4 pa; pa.x = pa.y = pa.z = pa.w = 0u;
      if (grow < M){
        if (kg < KA){
          if (AF32){
            const float* ap = (const float*)A1 + grow*s1 + kg;
            float4 f0 = *(const float4*)ap;
            float4 f1 = *(const float4*)(ap + 4);
            pa.x = pk(f0.x, f0.y); pa.y = pk(f0.z, f0.w);
            pa.z = pk(f1.x, f1.y); pa.w = pk(f1.z, f1.w);
          } else {
            pa = *(const uint4*)((const bf16*)A1 + grow*s1 + kg);
          }
        } else if (kg - KA < KB){
          pa = *(const uint4*)(A2 + grow*s2 + (kg - KA));
        }
      }
      tA[c] = pa;
    }
    #pragma unroll
    for (int c = 0; c < NKT; c++)
      ldsst16(&As[ra*AST + c*32 + ka], tA[c]);
  }
  __syncthreads();

  #pragma unroll
  for (int ks = 0; ks < NKT; ks++){
    #pragma unroll
    for (int j = 0; j < 4; j++)
      ldsst16(&Bs[(cb + j*64)*44 + kb], pb[j]);
    __syncthreads();

    if (ks + 1 < NKT) LOADB((ks + 1)*32);

    bf16x8 af[4], bfv[4];
    #pragma unroll
    for (int rt = 0; rt < 4; rt++)
      af[rt] = ldsld8(&As[(rt*16 + m16)*AST + ks*32 + q*8]);
    #pragma unroll
    for (int ct = 0; ct < 4; ct++)
      bfv[ct] = ldsld8(&Bs[(wc + ct*16 + m16)*44 + q*8]);
    #pragma unroll
    for (int rt = 0; rt < 4; rt++)
      #pragma unroll
      for (int ct = 0; ct < 4; ct++)
        acc[rt][ct] = __builtin_amdgcn_mfma_f32_16x16x32_bf16(af[rt], bfv[ct], acc[rt][ct], 0, 0, 0);
    __syncthreads();
  }
#undef LOADB

  #pragma unroll
  for (int rt = 0; rt < 4; rt++){
    #pragma unroll
    for (int rr = 0; rr < 4; rr++){
      int row = row0 + rt*16 + q*4 + rr;
      if (row >= M) continue;
      #pragma unroll
      for (int ct = 0; ct < 4; ct++){
        int col = wc + ct*16 + m16;
        if (col >= Ncols) continue;
        float v = acc[rt][ct][rr] + (bias ? bias[col] : 0.f);
        if (OUTMODE == 1) ((float*)Cp)[row*Cstride + col] = v;
        else {
          if (col < 80) ((bf16*)Cp )[row*80 + col]      = f2b(v);
          else          ((bf16*)Cp2)[row*80 + col - 80] = f2b(v);
        }
      }
    }
  }
}

// ------------------------------------------------------------------ fully-fused layer kernel
// agg (PNA stats) + GEMM2 + epilogue + next-layer GEMM1, one dispatch.
// Aggregation is done in the PROLOGUE with k_agg's proven per-thread footprint
// (16 f32: 4 features x 4 stats) via 5 feature-passes of (4 threads/node x
// 4 features); stats are written as bf16 pairs directly into the LDS A-panel
// at k in [80,400). colidx slice staged once into the (currently dead) Bs
// region. Eliminates the agg array (59MB/layer HBM round trip) + 4 dispatches.
// U is ping-pong buffered: reads Uar/Ubr (prev layer), tail writes Uaw/Ubw.
__global__ __launch_bounds__(256) void k_g2(
    const float* __restrict__ h,
    const bf16* __restrict__ Uar, const bf16* __restrict__ Ubr,
    const int* __restrict__ rowptr, const int* __restrict__ colidx,
    const bf16* __restrict__ Bt, const float* __restrict__ bias2v,
    const float* __restrict__ scf, const float* __restrict__ invf,
    float* __restrict__ hp,
    const bf16* __restrict__ Bt1n, const float* __restrict__ bias1n,
    bf16* __restrict__ Uaw, bf16* __restrict__ Ubw)
{
  constexpr int AST = 420, NKT = 13;
  __shared__ short As[64*AST];   // 53,760 B
  __shared__ short Bs[256*44];   // 22,528 B (total 76,288 -> 2 blocks/CU)
  __shared__ int nrp[65];
  bf16* eL = (bf16*)As;                 // epilogue staging 64x248 (<= 31,744 B)
  bf16* hA = (bf16*)(As + 16384);       // h_new panel 64x100 (bytes 32,768..45,568)

  const int tid = threadIdx.x;
  const int row0 = blockIdx.x * 64;
  const int wave = tid >> 6, lane = tid & 63;
  const int wc = wave * 64;
  const int m16 = lane & 15, q = lane >> 4;
  const int ra = tid >> 2, ka = (tid & 3) * 8;
  const int cb = tid >> 2, kb = (tid & 3) * 8;

  // ---- stage h rows (k<80) as bf16; zero pad k in [400,416)
  {
    int grow = row0 + ra;
    #pragma unroll
    for (int c = 0; c < 3; c++){
      int kg = c*32 + ka;
      if (kg < 80){
        uint4 pa; pa.x = pa.y = pa.z = pa.w = 0u;
        if (grow < NN){
          const float* ap = h + grow*80 + kg;
          float4 f0 = *(const float4*)ap;
          float4 f1 = *(const float4*)(ap + 4);
          pa.x = pk(f0.x, f0.y); pa.y = pk(f0.z, f0.w);
          pa.z = pk(f1.x, f1.y); pa.w = pk(f1.z, f1.w);
        }
        ldsst16(&As[ra*AST + kg], pa);
      }
    }
    if (ka == 24){
      uint4 z; z.x = z.y = z.z = z.w = 0u;
      ldsst16(&As[ra*AST + 400], z);
      ldsst16(&As[ra*AST + 408], z);
    }
  }

  // ---- rowptr slice + colidx slice into LDS (Bs region, dead until main loop)
  int* ci = (int*)Bs;    // up to BCAP edges
  if (tid < 65){
    int n = row0 + tid;
    nrp[tid] = rowptr[n < NN ? n : NN];
  }
  __syncthreads();
  const int e0 = nrp[0];
  const int ecnt = nrp[64] - e0;
  const bool inl = (ecnt <= BCAP);
  if (inl)
    for (int i = tid; i < ecnt; i += 256) ci[i] = colidx[e0 + i];
  __syncthreads();

  // ---- fused PNA aggregation: 5 passes x (4 threads/node x 4 features)
  {
    int s = tid >> 2, p = tid & 3;
    int n = row0 + s;
    int na = n < NN ? n : NN - 1;
    int rs = nrp[s] - e0, re = nrp[s+1] - e0;
    int deg = re - rs;
    float dm = (float)deg;
    float inv = 1.f / fmaxf(dm, 1.f);
    short* st = &As[s*AST];
#define ACCW(w, o) { \
    float b0 = __uint_as_float((w) << 16); \
    float b1 = __uint_as_float((w) & 0xffff0000u); \
    sb[o] += b0; sq[o] += b0*b0; mn[o] = fminf(mn[o],b0); mx[o] = fmaxf(mx[o],b0); \
    sb[o+1] += b1; sq[o+1] += b1*b1; mn[o+1] = fminf(mn[o+1],b1); mx[o+1] = fmaxf(mx[o+1],b1); }
    #pragma unroll 1
    for (int pass = 0; pass < 5; pass++){
      int fo = pass*16 + p*4;
      float sb[4] = {0.f,0.f,0.f,0.f}, sq[4] = {0.f,0.f,0.f,0.f};
      float mn[4] = {1e30f,1e30f,1e30f,1e30f}, mx[4] = {-1e30f,-1e30f,-1e30f,-1e30f};
      for (int e = rs; e < re; e += 8){
        int cnb = re - e; if (cnb > 8) cnb = 8;
        int src[8];
        #pragma unroll
        for (int j = 0; j < 8; j++)
          src[j] = (j < cnb) ? (inl ? ci[e + j] : colidx[e0 + e + j]) : src[0];
        uint2 u[8];
        #pragma unroll
        for (int j = 0; j < 8; j++) u[j] = *(const uint2*)(Ubr + src[j]*80 + fo);
        #pragma unroll
        for (int j = 0; j < 8; j++){
          if (j < cnb){ ACCW(u[j].x, 0); ACCW(u[j].y, 2); }
        }
      }
      // self features
      float av[4];
      {
        uint2 us = *(const uint2*)(Uar + na*80 + fo);
        av[0] = __uint_as_float(us.x << 16);
        av[1] = __uint_as_float(us.x & 0xffff0000u);
        av[2] = __uint_as_float(us.y << 16);
        av[3] = __uint_as_float(us.y & 0xffff0000u);
      }
      float mean[4], lo[4], hi[4], sd[4];
      #pragma unroll
      for (int i = 0; i < 4; i++){
        float a = av[i];
        mean[i] = (dm*a + sb[i])*inv;
        float v = (dm*a*a + 2.f*a*sb[i] + sq[i])*inv - mean[i]*mean[i];
        sd[i] = sqrtf(fmaxf(v, 0.f) + 1e-5f);
        lo[i] = deg > 0 ? a + mn[i] : 0.f;
        hi[i] = deg > 0 ? a + mx[i] : 0.f;
      }
      *(unsigned*)(st +  80 + fo)     = pk(mean[0], mean[1]);
      *(unsigned*)(st +  80 + fo + 2) = pk(mean[2], mean[3]);
      *(unsigned*)(st + 160 + fo)     = pk(lo[0], lo[1]);
      *(unsigned*)(st + 160 + fo + 2) = pk(lo[2], lo[3]);
      *(unsigned*)(st + 240 + fo)     = pk(hi[0], hi[1]);
      *(unsigned*)(st + 240 + fo + 2) = pk(hi[2], hi[3]);
      *(unsigned*)(st + 320 + fo)     = pk(sd[0], sd[1]);
      *(unsigned*)(st + 320 + fo + 2) = pk(sd[2], sd[3]);
    }
#undef ACCW
  }

  // ---- B tile 0 into regs (issued before the barrier; overlaps it)
  uint4 pb[4];
#define LOADB2(k0_) { int kgb = (k0_) + kb;                                    \
    _Pragma("unroll")                                                          \
    for (int j = 0; j < 4; j++){                                               \
      int col = cb + j*64;                                                     \
      pb[j].x = pb[j].y = pb[j].z = pb[j].w = 0u;                              \
      if (col < 240) pb[j] = *(const uint4*)(Bt + col*416 + kgb);              \
    } }
  LOADB2(0);
  __syncthreads();   // A panel complete; ci no longer needed

  f32x4 acc[4][4] = {};

  // ---- main K loop (r4 structure)
  #pragma unroll
  for (int ks = 0; ks < NKT; ks++){
    #pragma unroll
    for (int j = 0; j < 4; j++)
      ldsst16(&Bs[(cb + j*64)*44 + kb], pb[j]);
    __syncthreads();

    if (ks + 1 < NKT) LOADB2((ks + 1)*32);

    bf16x8 af[4], bfv[4];
    #pragma unroll
    for (int rt = 0; rt < 4; rt++)
      af[rt] = ldsld8(&As[(rt*16 + m16)*AST + ks*32 + q*8]);
    #pragma unroll
    for (int ct = 0; ct < 4; ct++)
      bfv[ct] = ldsld8(&Bs[(wc + ct*16 + m16)*44 + q*8]);
    #pragma unroll
    for (int rt = 0; rt < 4; rt++)
      #pragma unroll
      for (int ct = 0; ct < 4; ct++)
        acc[rt][ct] = __builtin_amdgcn_mfma_f32_16x16x32_bf16(af[rt], bfv[ct], acc[rt][ct], 0, 0, 0);
    __syncthreads();
  }
#undef LOADB2

  // ---- preload mini-GEMM B tile 0 (overlaps epilogue)
  uint4 pb1[4];
  if (Bt1n){
    #pragma unroll
    for (int j = 0; j < 4; j++){
      int col = cb + j*64;
      pb1[j].x = pb1[j].y = pb1[j].z = pb1[j].w = 0u;
      if (col < 160) pb1[j] = *(const uint4*)(Bt1n + col*96 + kb);
    }
  }

  // ---- epilogue: stage P|Q|R in eL
  #pragma unroll
  for (int rt = 0; rt < 4; rt++){
    #pragma unroll
    for (int ct = 0; ct < 4; ct++){
      int col = wc + ct*16 + m16;
      if (col >= 240) continue;
      #pragma unroll
      for (int rr = 0; rr < 4; rr++){
        int r = rt*16 + q*4 + rr;
        eL[r*248 + col] = f2b(acc[rt][ct][rr]);
      }
    }
  }
  __syncthreads();

  // ---- combine -> h_new; write global f32 + LDS bf16 panel
  #pragma unroll
  for (int i = 0; i < 20; i++){
    int idx = tid + i*256;
    int r = idx / 80, c = idx - r*80;
    int row = row0 + r;
    if (row < NN){
      float P = b2f(eL[r*248 + c]);
      float Q = b2f(eL[r*248 + 80 + c]);
      float R = b2f(eL[r*248 + 160 + c]);
      float o = P + scf[row]*Q + invf[row]*R + bias2v[c];
      float hn = hp[row*80 + c] + fmaxf(o, 0.f);
      hp[row*80 + c] = hn;
      if (Bt1n) hA[r*100 + c] = f2b(hn);
    } else if (Bt1n && idx < 64*80){
      hA[r*100 + c] = f2b(0.f);   // tail rows: defined values for mini-GEMM
    }
  }
  if (Bt1n){
    // zero pad k in [80,96)
    int r = tid >> 2, off = 80 + (tid & 3)*4;
    *(uint2*)&hA[r*100 + off] = make_uint2(0u, 0u);
  }
  __syncthreads();

  // ---- mini-GEMM: U = h_new @ Bt1[next] (K=96, 160 cols), write Uaw/Ubw
  if (Bt1n){
    f32x4 acc2[4][4] = {};
    #pragma unroll
    for (int ks = 0; ks < 3; ks++){
      #pragma unroll
      for (int j = 0; j < 4; j++)
        ldsst16(&Bs[(cb + j*64)*44 + kb], pb1[j]);
      __syncthreads();

      if (ks + 1 < 3){
        int kgb = (ks + 1)*32 + kb;
        #pragma unroll
        for (int j = 0; j < 4; j++){
          int col = cb + j*64;
          pb1[j].x = pb1[j].y = pb1[j].z = pb1[j].w = 0u;
          if (col < 160) pb1[j] = *(const uint4*)(Bt1n + col*96 + kgb);
        }
      }

      bf16x8 af[4], bfv[4];
      #pragma unroll
      for (int rt = 0; rt < 4; rt++)
        af[rt] = ldsld8((const short*)hA + (rt*16 + m16)*100 + ks*32 + q*8);
      #pragma unroll
      for (int ct = 0; ct < 4; ct++)
        bfv[ct] = ldsld8(&Bs[(wc + ct*16 + m16)*44 + q*8]);
      #pragma unroll
      for (int rt = 0; rt < 4; rt++)
        #pragma unroll
        for (int ct = 0; ct < 4; ct++)
          acc2[rt][ct] = __builtin_amdgcn_mfma_f32_16x16x32_bf16(af[rt], bfv[ct], acc2[rt][ct], 0, 0, 0);
      __syncthreads();
    }
    #pragma unroll
    for (int rt = 0; rt < 4; rt++){
      #pragma unroll
      for (int rr = 0; rr < 4; rr++){
        int row = row0 + rt*16 + q*4 + rr;
        if (row >= NN) continue;
        #pragma unroll
        for (int ct = 0; ct < 4; ct++){
          int col = wc + ct*16 + m16;
          if (col >= 160) continue;
          float v = acc2[rt][ct][rr] + bias1n[col];
          if (col < 80) Uaw[row*80 + col]      = f2b(v);
          else          Ubw[row*80 + col - 80] = f2b(v);
        }
      }
    }
  }
}

// ------------------------------------------------------------------ fused mean-pool + head
__global__ __launch_bounds__(128) void k_poolmlp(const float* __restrict__ h,
                        const int* __restrict__ batch,
                        const void* __restrict__ mlpW, const void* __restrict__ mlpb,
                        const int* __restrict__ flag, void* __restrict__ outp){
  __shared__ float sred[128];
  __shared__ int sb[2];
  int g = blockIdx.x;
  int t = threadIdx.x;
  if (t < 2){
    int target = g + t;
    int lo = 0, hi = NN;
    while (lo < hi){ int mid = (lo + hi) >> 1; if (batch[mid] < target) lo = mid + 1; else hi = mid; }
    sb[t] = lo;
  }
  __syncthreads();
  int lo = sb[0], hi = sb[1];
  float s = 0.f;
  if (t < 80)
    for (int n = lo; n < hi; n++) s += h[n*80 + t];
  int fl = flag[0];
  float wv = (t < 80) ? rdw(mlpW, t, fl) : 0.f;
  sred[t] = s * wv;
  __syncthreads();
  for (int off = 64; off > 0; off >>= 1){
    if (t < off) sred[t] += sred[t + off];
    __syncthreads();
  }
  if (t == 0){
    float cnt = (float)(hi - lo); if (cnt < 1.f) cnt = 1.f;
    float r = sred[0]/cnt + rdw(mlpb, 0, fl);
    if (fl) ((float*)outp)[g] = r;
    else    ((bf16*)outp)[g] = f2b(r);
  }
}

// ------------------------------------------------------------------ launch
extern "C" void kernel_launch(void* const* d_in, const int* in_sizes, int n_in,
                              void* d_out, int out_size, void* d_ws, size_t ws_size,
                              hipStream_t stream)
{
  const int*  x     = (const int*) d_in[0];
  const int*  ei    = (const int*) d_in[1];
  const int*  batch = (const int*) d_in[2];
  const void* avgp  = d_in[3];
  const void* aemb  = d_in[4];
  const void* preW  = d_in[5];
  const void* preb  = d_in[6];
  const void* postW = d_in[7];
  const void* postb = d_in[8];
  const void* linW  = d_in[9];
  const void* linb  = d_in[10];
  const void* bng   = d_in[11];
  const void* bnb   = d_in[12];
  const void* bnm   = d_in[13];
  const void* bnv   = d_in[14];
  const void* mlpW  = d_in[15];
  const void* mlpb  = d_in[16];

  char* w = (char*)d_ws;
  int*   flag   = (int*)  (w + 400000);       //       256  (zeroed)
  int*   rowptr = (int*)  (w + 401280);       //   200,064
  int*   colidx = (int*)  (w + 601344);       // 3,200,000
  float* scf    = (float*)(w + 3801344);      //   200,000
  float* invf   = (float*)(w + 4001344);      //   200,000
  float* bias1  = (float*)(w + 4201344);      //     2,560
  float* bias2  = (float*)(w + 4203904);      //     1,280
  bf16*  Btl    = (bf16*) (w + 4205184);      //    61,440
  bf16*  Bt1    = (bf16*) (w + 4266624);      //   122,880
  bf16*  Bt2    = (bf16*) (w + 4389504);      //   798,720
  float* h      = (float*)(w + 5188224);      // 16,000,000  f32 [N,80]
  bf16*  UaA    = (bf16*) (w + 21188224);     //  8,000,000  bf16 [N,80]
  bf16*  UbA    = (bf16*) (w + 29188224);     //  8,000,000  bf16 [N,80]
  bf16*  UaB    = (bf16*) (w + 45188224);     //  8,000,000  (ping-pong, ex-agg region)
  bf16*  UbB    = (bf16*) (w + 53188224);     //  8,000,000
  // pre-loop overlays inside the UaB/UbB region (all consumed before layer 0):
  bf16*  pwb    = (bf16*) (w + 61188224);     //   665,600
  float* Wf     = (float*)(w + 61853824);     // 1,331,200
  int* staging  = (int*)  (w + 63185024);     // 3,200,000
  int* chunkcnt = (int*)  (w + 66385024);     // 2,446,096  [NCH][NBUCK]
  int* btotal   = (int*)  (w + 68831120);     //     3,128
  int* bbase    = (int*)  (w + 68834248);     //     3,136  (NBUCK+1)
  // total 77,188,224 B (end 68,837,384)

  k_zero <<<1, 256, 0, stream>>>(flag, 64);
  k_probe<<<16, 256, 0, stream>>>(aemb, flag);

  // atomic-free CSR build
  k_hist <<<NCH, 256, 0, stream>>>(ei, chunkcnt);
  k_cscan<<<NBUCK, 256, 0, stream>>>(chunkcnt, btotal);
  k_bscan<<<1, 256, 0, stream>>>(btotal, bbase);
  k_place<<<NCH, 256, 0, stream>>>(ei, chunkcnt, bbase, staging);

  k_prep_all<<<1662, 256, 0, stream>>>(preW, preb, postW, postb, linW, linb,
                                       bng, bnb, bnm, bnv, flag,
                                       pwb, Btl, Bt1, bias1, bias2);

  // Wf[i] = postW[i](bf16) @ Btl[i]^T   (f32 out)
  k_mgemm<0,1,96,100><<<dim3(17,1,4), 256, 0, stream>>>(
      pwb, 80, 80, nullptr, 0, 0,
      Btl, 96, 80, nullptr, Wf, nullptr, 80, 1040,
      166400, 15360, 332800);
  k_prep_Bt2<<<(4*240*416 + 255)/256, 256, 0, stream>>>(Wf, Bt2);

  k_atom <<<(NN*FD + 255)/256, 256, 0, stream>>>(x, aemb, flag, h);

  // fused rowptr/scf/invf + counting-sorted colidx
  k_csr<<<NBUCK, 256, 0, stream>>>(staging, bbase, avgp, flag, rowptr, scf, invf, colidx);

  const int gx = (NN + 63)/64;   // 782
  // layer-0 GEMM1 (subsequent layers' GEMM1 are fused into k_g2's tail)
  k_mgemm<1,2,96,100><<<dim3(gx,1,1), 256, 0, stream>>>(
      h, 80, 80, nullptr, 0, 0,
      Bt1, 96, 160, bias1, UaA, UbA, 0, NN,
      0, 0, 0);
  for (int i = 0; i < 4; i++){
    const bf16* Uar = (i & 1) ? UaB : UaA;
    const bf16* Ubr = (i & 1) ? UbB : UbA;
    bf16* Uaw = (i & 1) ? UaA : UaB;
    bf16* Ubw = (i & 1) ? UbA : UbB;
    const bf16* nBt1 = (i < 3) ? (Bt1 + (i+1)*15360) : nullptr;
    const float* nb1 = (i < 3) ? (bias1 + (i+1)*160) : bias1;
    k_g2<<<dim3(gx,1,1), 256, 0, stream>>>(
        h, Uar, Ubr, rowptr, colidx,
        Bt2 + i*99840, bias2 + i*80, scf, invf, h,
        nBt1, nb1, Uaw, Ubw);
  }

  k_poolmlp<<<NGR, 128, 0, stream>>>(h, batch, mlpW, mlpb, flag, d_out);
}

// Round 10
// 586.755 us; speedup vs baseline: 1.2381x; 1.2381x over previous
//
#include <hip/hip_runtime.h>
#include <hip/hip_bf16.h>

#define NN 50000
#define NE 800000
#define FD 80
#define NGR 1024
#define NF 9

// bucketed CSR sort (atomic-free counting sort)
#define BSH 6
#define NBUCK ((NN + 63) >> 6)     // 782 node-buckets of 64
#define CSH 12
#define NCH ((NE + 4095) >> 12)    // 196 edge-chunks of 4096
#define BCAP 2048

using bf16 = __hip_bfloat16;
typedef __attribute__((ext_vector_type(8))) short bf16x8;
typedef __attribute__((ext_vector_type(4))) float f32x4;

static __device__ __forceinline__ float b2f(bf16 v){ return __bfloat162float(v); }
static __device__ __forceinline__ bf16 f2b(float v){ return __float2bfloat16(v); }
static __device__ __forceinline__ float rdw(const void* p, int i, int fl){
  return fl ? ((const float*)p)[i] : b2f(((const bf16*)p)[i]);
}
static __device__ __forceinline__ unsigned pk(float a, float b){
  bf16 x = f2b(a), y = f2b(b);
  return (unsigned)*(unsigned short*)&x | ((unsigned)*(unsigned short*)&y << 16);
}
// 8B-granule LDS access (strides are 8B- but not 16B-aligned)
static __device__ __forceinline__ bf16x8 ldsld8(const short* p){
  union { bf16x8 v; uint2 u[2]; } r;
  r.u[0] = *(const uint2*)(p);
  r.u[1] = *(const uint2*)(p + 4);
  return r.v;
}
static __device__ __forceinline__ void ldsst16(short* p, uint4 v){
  *(uint2*)(p)     = make_uint2(v.x, v.y);
  *(uint2*)(p + 4) = make_uint2(v.z, v.w);
}

// ------------------------------------------------------------------ utility
__global__ void k_zero(int* __restrict__ p, int n){
  int t = blockIdx.x*256 + threadIdx.x;
  if (t < n) p[t] = 0;
}

__global__ void k_probe(const void* __restrict__ emb, int* __restrict__ flag){
  int t = blockIdx.x*256 + threadIdx.x;
  float v = b2f(((const bf16*)emb)[t]);
  if (!(fabsf(v) < 1e4f)) atomicOr(flag, 1);
}

// ------------------------------------------------------------------ fused weight prep
__global__ __launch_bounds__(256) void k_prep_all(
    const void* __restrict__ preW, const void* __restrict__ preb,
    const void* __restrict__ postW, const void* __restrict__ postb,
    const void* __restrict__ linW, const void* __restrict__ linb,
    const void* __restrict__ bng, const void* __restrict__ bnb,
    const void* __restrict__ bnm, const void* __restrict__ bnv,
    const int* __restrict__ flag,
    bf16* __restrict__ pwb, bf16* __restrict__ Btl, bf16* __restrict__ Bt1,
    float* __restrict__ bias1, float* __restrict__ bias2)
{
  int fl = flag[0];
  int b = blockIdx.x;
  if (b < 1300){
    int t = b*256 + threadIdx.x;
    pwb[t] = f2b(rdw(postW, t, fl));
  } else if (b < 1420){
    int t = (b - 1300)*256 + threadIdx.x;
    int j = t % 96, c = (t/96) % 80, i = t/(96*80);
    float v = 0.f;
    if (j < 80){
      float gs = rdw(bng, i*80 + c, fl) * rsqrtf(rdw(bnv, i*80 + c, fl) + 1e-5f);
      v = rdw(linW, i*6400 + j*80 + c, fl) * gs;
    }
    Btl[t] = f2b(v);
  } else if (b < 1660){
    int t = (b - 1420)*256 + threadIdx.x;
    int k = t % 96, c = (t/96) % 160, i = t/(96*160);
    float v = 0.f;
    if (k < 80)
      v = (c < 80) ? rdw(preW, (i*160 + k)*80 + c, fl)
                   : rdw(preW, (i*160 + 80 + k)*80 + (c - 80), fl);
    Bt1[t] = f2b(v);
    if (k == 0) bias1[i*160 + c] = (c < 80) ? rdw(preb, i*80 + c, fl) : 0.f;
  } else {
    int t = (b - 1660)*256 + threadIdx.x;
    if (t >= 4*80) return;
    int i = t / 80, f = t - i*80;
    float s = 0.f;
    for (int j = 0; j < 80; j++)
      s += rdw(postb, i*80 + j, fl) * rdw(linW, (i*80 + j)*80 + f, fl);
    s += rdw(linb, t, fl);
    float gs = rdw(bng, t, fl) * rsqrtf(rdw(bnv, t, fl) + 1e-5f);
    bias2[t] = (s - rdw(bnm, t, fl)) * gs + rdw(bnb, t, fl);
  }
}

// Bt2[i][c][k] (c<240 cols, 416-k) from Wf (f32 [i][1040][80]).
__global__ void k_prep_Bt2(const float* __restrict__ Wf, bf16* __restrict__ Bt2){
  int t = blockIdx.x*256 + threadIdx.x;
  if (t >= 4*240*416) return;
  int k = t % 416;
  int c = (t/416) % 240;
  int i = t/(416*240);
  float v = 0.f;
  if (k < 400){
    int blk = c/80, f = c - blk*80;
    if (blk == 0) v = Wf[(i*1040 + k)*80 + f];
    else if (k >= 80){
      int row = (blk == 1 ? 400 : 720) + (k - 80);
      v = Wf[(i*1040 + row)*80 + f];
    }
  }
  Bt2[t] = f2b(v);
}

// ------------------------------------------------------------------ graph prep
// Vectorized: one thread per (node, 8-feature block); 9 x 16B gathers + float4
// stores (was: 1 thread/element x 9 scalar loads = 8x more load instrs).
// Summation order (c ascending) identical to the scalar version.
__global__ void k_atom(const int* __restrict__ x, const void* __restrict__ emb,
                       const int* __restrict__ flag, float* __restrict__ h){
  int fl = flag[0];
  int gid = blockIdx.x*256 + threadIdx.x;
  if (gid >= NN*10) return;
  int n = gid / 10, fb = gid - n*10;
  int f0 = fb*8;
  int xr[NF];
  #pragma unroll
  for (int c = 0; c < NF; c++) xr[c] = x[n*NF + c];
  float s[8] = {0.f,0.f,0.f,0.f,0.f,0.f,0.f,0.f};
  if (fl){
    #pragma unroll
    for (int c = 0; c < NF; c++){
      const float* ep = (const float*)emb + (c*119 + xr[c])*80 + f0;
      float4 a = *(const float4*)ep, b = *(const float4*)(ep + 4);
      s[0]+=a.x; s[1]+=a.y; s[2]+=a.z; s[3]+=a.w;
      s[4]+=b.x; s[5]+=b.y; s[6]+=b.z; s[7]+=b.w;
    }
  } else {
    #pragma unroll
    for (int c = 0; c < NF; c++){
      const bf16* ep = (const bf16*)emb + (c*119 + xr[c])*80 + f0;
      uint4 u = *(const uint4*)ep;
      s[0]+=__uint_as_float(u.x<<16); s[1]+=__uint_as_float(u.x&0xffff0000u);
      s[2]+=__uint_as_float(u.y<<16); s[3]+=__uint_as_float(u.y&0xffff0000u);
      s[4]+=__uint_as_float(u.z<<16); s[5]+=__uint_as_float(u.z&0xffff0000u);
      s[6]+=__uint_as_float(u.w<<16); s[7]+=__uint_as_float(u.w&0xffff0000u);
    }
  }
  float* hp = h + n*80 + f0;
  *(float4*)hp       = make_float4(s[0],s[1],s[2],s[3]);
  *(float4*)(hp + 4) = make_float4(s[4],s[5],s[6],s[7]);
}

// ---- atomic-free CSR build: hist -> cscan -> bscan -> place -> csr ----

// Per-chunk bucket histogram (coalesced matrix write). 4096 edges/chunk.
__global__ __launch_bounds__(256) void k_hist(const int* __restrict__ ei,
                                              int* __restrict__ chunkcnt){
  __shared__ int hist[NBUCK];
  int c = blockIdx.x, t = threadIdx.x;
  for (int i = t; i < NBUCK; i += 256) hist[i] = 0;
  __syncthreads();
  #pragma unroll
  for (int j = 0; j < 16; j++){
    int e = (c << CSH) + j*256 + t;
    if (e < NE) atomicAdd(&hist[ei[NE + e] >> BSH], 1);
  }
  __syncthreads();
  for (int i = t; i < NBUCK; i += 256) chunkcnt[c*NBUCK + i] = hist[i];
}

// Per-bucket exclusive scan over chunks (in-place) + bucket totals.
__global__ __launch_bounds__(256) void k_cscan(int* __restrict__ chunkcnt,
                                               int* __restrict__ btotal){
  __shared__ int buf[256];
  int b = blockIdx.x, t = threadIdx.x;
  int v[4]; int s = 0;
  #pragma unroll
  for (int j = 0; j < 4; j++){
    int c = t*4 + j;
    v[j] = (c < NCH) ? chunkcnt[c*NBUCK + b] : 0;
    s += v[j];
  }
  buf[t] = s;
  __syncthreads();
  for (int off = 1; off < 256; off <<= 1){
    int xv = (t >= off) ? buf[t - off] : 0;
    __syncthreads();
    buf[t] += xv;
    __syncthreads();
  }
  int excl = buf[t] - s;
  #pragma unroll
  for (int j = 0; j < 4; j++){
    int c = t*4 + j;
    if (c < NCH){ chunkcnt[c*NBUCK + b] = excl; excl += v[j]; }
  }
  if (t == 255) btotal[b] = buf[255];
}

// Exclusive scan of bucket totals -> bucket base offsets (bbase[NBUCK] = NE).
__global__ __launch_bounds__(256) void k_bscan(const int* __restrict__ btotal,
                                               int* __restrict__ bbase){
  __shared__ int buf[256];
  int t = threadIdx.x;
  int v[4]; int s = 0;
  #pragma unroll
  for (int j = 0; j < 4; j++){
    int c = t*4 + j;
    v[j] = (c < NBUCK) ? btotal[c] : 0;
    s += v[j];
  }
  buf[t] = s;
  __syncthreads();
  for (int off = 1; off < 256; off <<= 1){
    int xv = (t >= off) ? buf[t - off] : 0;
    __syncthreads();
    buf[t] += xv;
    __syncthreads();
  }
  int excl = buf[t] - s;
  #pragma unroll
  for (int j = 0; j < 4; j++){
    int c = t*4 + j;
    if (c < NBUCK){ bbase[c] = excl; excl += v[j]; }
  }
  if (t == 255) bbase[NBUCK] = buf[255];
}

// Place each edge into its bucket's staging range; rank via LDS atomics.
__global__ __launch_bounds__(256) void k_place(const int* __restrict__ ei,
                        const int* __restrict__ chunkcnt, const int* __restrict__ bbase,
                        int* __restrict__ staging){
  __shared__ int basep[NBUCK];
  __shared__ int cur[NBUCK];
  int c = blockIdx.x, t = threadIdx.x;
  for (int i = t; i < NBUCK; i += 256){
    basep[i] = chunkcnt[c*NBUCK + i] + bbase[i];
    cur[i] = 0;
  }
  __syncthreads();
  #pragma unroll
  for (int j = 0; j < 16; j++){
    int e = (c << CSH) + j*256 + t;
    if (e < NE){
      int d = ei[NE + e], s = ei[e];
      int b = d >> BSH;
      int r = atomicAdd(&cur[b], 1);
      staging[basep[b] + r] = (s << BSH) | (d & 63);
    }
  }
}

// Fused per-bucket finalize: node counts -> rowptr/scf/invf + counting sort
// into colidx (sequential reads, coalesced writes).
__global__ __launch_bounds__(256) void k_csr(const int* __restrict__ staging,
                        const int* __restrict__ bbase, const void* __restrict__ avgp,
                        const int* __restrict__ flag, int* __restrict__ rowptr,
                        float* __restrict__ scf, float* __restrict__ invf,
                        int* __restrict__ colidx){
  __shared__ int lcnt[64], lrp[64], lcur[64];
  __shared__ int colbuf[BCAP];
  int b = blockIdx.x, t = threadIdx.x;
  int base = bbase[b];
  int cnt  = bbase[b+1] - base;
  if (t < 64){ lcnt[t] = 0; lcur[t] = 0; }
  __syncthreads();
  for (int i = t; i < cnt; i += 256)
    atomicAdd(&lcnt[staging[base + i] & 63], 1);
  __syncthreads();
  if (t < 64) lrp[t] = lcnt[t];
  __syncthreads();
  for (int off = 1; off < 64; off <<= 1){
    int xv = (t < 64 && t >= off) ? lrp[t - off] : 0;
    __syncthreads();
    if (t < 64) lrp[t] += xv;
    __syncthreads();
  }
  int n0 = b << BSH;
  if (t < 64){
    int ex = lrp[t] - lcnt[t];
    lrp[t] = ex;
    int n = n0 + t;
    if (n < NN){
      rowptr[n] = base + ex;
      float degc = (float)(lcnt[t] > 0 ? lcnt[t] : 1);
      float logd = logf(degc + 1.f);
      float avg = rdw(avgp, 0, flag[0]);
      scf[n] = logd / avg;
      invf[n] = avg / logd;
    }
  }
  if (b == 0 && t == 0) rowptr[NN] = NE;
  __syncthreads();
  if (cnt <= BCAP){
    for (int i = t; i < cnt; i += 256){
      int v = staging[base + i];
      int l = v & 63;
      int pos = lrp[l] + atomicAdd(&lcur[l], 1);
      colbuf[pos] = v >> BSH;
    }
    __syncthreads();
    for (int i = t; i < cnt; i += 256)
      colidx[base + i] = colbuf[i];
  } else {
    for (int i = t; i < cnt; i += 256){
      int v = staging[base + i];
      int l = v & 63;
      int pos = lrp[l] + atomicAdd(&lcur[l], 1);
      colidx[base + pos] = v >> BSH;
    }
  }
}

// ------------------------------------------------------------------ MFMA GEMM (r4 structure, best measured)
// 64-row x 256-col block tile, 4 waves. Full A-panel staged to LDS up-front,
// K-loop streams B via reg->LDS with prefetch. Used for Wf (OUTMODE1) and
// layer-0 GEMM1 (OUTMODE2).
template<int AF32, int OUTMODE, int K_, int AST>
__global__ __launch_bounds__(256) void k_mgemm(
    const void* __restrict__ A1p, int s1, int KA,
    const bf16* __restrict__ A2, int s2, int KB,
    const bf16* __restrict__ Btp, int Bts, int Ncols,
    const float* __restrict__ bias,
    void* __restrict__ Cbase, void* __restrict__ Cp2, int Cstride, int M,
    int lA1b, int lBtb, int lCb)
{
  const void* A1 = (const char*)A1p + (size_t)blockIdx.z*lA1b;
  const bf16* Bt = (const bf16*)((const char*)Btp + (size_t)blockIdx.z*lBtb);
  void* Cp = (char*)Cbase + (size_t)blockIdx.z*lCb;

  constexpr int NKT = K_ / 32;
  __shared__ short As[64*AST];
  __shared__ short Bs[256*44];

  const int tid = threadIdx.x;
  const int row0 = blockIdx.x * 64;
  const int wave = tid >> 6, lane = tid & 63;
  const int wc = wave * 64;
  const int m16 = lane & 15, q = lane >> 4;

  const int ra = tid >> 2, ka = (tid & 3) * 8;
  const int cb = tid >> 2, kb = (tid & 3) * 8;

  f32x4 acc[4][4] = {};
  uint4 pb[4];

#define LOADB(k0_) { int kgb = (k0_) + kb;                                     \
    _Pragma("unroll")                                                          \
    for (int j = 0; j < 4; j++){                                               \
      int col = cb + j*64;                                                     \
      pb[j].x = pb[j].y = pb[j].z = pb[j].w = 0u;                              \
      if (col < Ncols) pb[j] = *(const uint4*)(Bt + col*Bts + kgb);            \
    } }

  LOADB(0);

  {
    const int grow = row0 + ra;
    uint4 tA[NKT];
    #pragma unroll
    for (int c = 0; c < NKT; c++){
      int kg = c*32 + ka;
      uint4 pa; pa.x = pa.y = pa.z = pa.w = 0u;
      if (grow < M){
        if (kg < KA){
          if (AF32){
            const float* ap = (const float*)A1 + grow*s1 + kg;
            float4 f0 = *(const float4*)ap;
            float4 f1 = *(const float4*)(ap + 4);
            pa.x = pk(f0.x, f0.y); pa.y = pk(f0.z, f0.w);
            pa.z = pk(f1.x, f1.y); pa.w = pk(f1.z, f1.w);
          } else {
            pa = *(const uint4*)((const bf16*)A1 + grow*s1 + kg);
          }
        } else if (kg - KA < KB){
          pa = *(const uint4*)(A2 + grow*s2 + (kg - KA));
        }
      }
      tA[c] = pa;
    }
    #pragma unroll
    for (int c = 0; c < NKT; c++)
      ldsst16(&As[ra*AST + c*32 + ka], tA[c]);
  }
  __syncthreads();

  #pragma unroll
  for (int ks = 0; ks < NKT; ks++){
    #pragma unroll
    for (int j = 0; j < 4; j++)
      ldsst16(&Bs[(cb + j*64)*44 + kb], pb[j]);
    __syncthreads();

    if (ks + 1 < NKT) LOADB((ks + 1)*32);

    bf16x8 af[4], bfv[4];
    #pragma unroll
    for (int rt = 0; rt < 4; rt++)
      af[rt] = ldsld8(&As[(rt*16 + m16)*AST + ks*32 + q*8]);
    #pragma unroll
    for (int ct = 0; ct < 4; ct++)
      bfv[ct] = ldsld8(&Bs[(wc + ct*16 + m16)*44 + q*8]);
    #pragma unroll
    for (int rt = 0; rt < 4; rt++)
      #pragma unroll
      for (int ct = 0; ct < 4; ct++)
        acc[rt][ct] = __builtin_amdgcn_mfma_f32_16x16x32_bf16(af[rt], bfv[ct], acc[rt][ct], 0, 0, 0);
    __syncthreads();
  }
#undef LOADB

  #pragma unroll
  for (int rt = 0; rt < 4; rt++){
    #pragma unroll
    for (int rr = 0; rr < 4; rr++){
      int row = row0 + rt*16 + q*4 + rr;
      if (row >= M) continue;
      #pragma unroll
      for (int ct = 0; ct < 4; ct++){
        int col = wc + ct*16 + m16;
        if (col >= Ncols) continue;
        float v = acc[rt][ct][rr] + (bias ? bias[col] : 0.f);
        if (OUTMODE == 1) ((float*)Cp)[row*Cstride + col] = v;
        else {
          if (col < 80) ((bf16*)Cp )[row*80 + col]      = f2b(v);
          else          ((bf16*)Cp2)[row*80 + col - 80] = f2b(v);
        }
      }
    }
  }
}

// ------------------------------------------------------------------ GEMM2 + fused next-layer GEMM1 (r8 form, best measured)
// r4's GEMM2 (OUTMODE 3) verbatim, plus a tail: the epilogue's h_new (64 rows)
// is stored bf16 into a small LDS panel (stride 100 shorts = 50 dwords;
// gcd(50,32)=2 -> 16 fragment rows hit distinct banks), then a 3-k-step
// mini-GEMM against next layer's Bt1 (L2-hot, 30KB) produces Ua/Ub directly.
__global__ __launch_bounds__(256) void k_g2(
    const float* __restrict__ h, const bf16* __restrict__ agg,
    const bf16* __restrict__ Bt, const float* __restrict__ bias2v,
    const float* __restrict__ scf, const float* __restrict__ invf,
    float* __restrict__ hp,
    const bf16* __restrict__ Bt1n, const float* __restrict__ bias1n,
    bf16* __restrict__ Ua, bf16* __restrict__ Ub)
{
  constexpr int AST = 420, NKT = 13;
  __shared__ short As[64*AST];   // 53,760 B
  __shared__ short Bs[256*44];   // 22,528 B (total 76,288 -> 2 blocks/CU, as r4)
  bf16* eL = (bf16*)As;                 // epilogue staging 64x248 (ends at byte 31,744)
  bf16* hA = (bf16*)(As + 16384);       // h_new panel 64x100 (bytes 32,768..45,568)

  const int tid = threadIdx.x;
  const int row0 = blockIdx.x * 64;
  const int wave = tid >> 6, lane = tid & 63;
  const int wc = wave * 64;
  const int m16 = lane & 15, q = lane >> 4;
  const int ra = tid >> 2, ka = (tid & 3) * 8;
  const int cb = tid >> 2, kb = (tid & 3) * 8;

  f32x4 acc[4][4] = {};
  uint4 pb[4];

#define LOADB2(k0_) { int kgb = (k0_) + kb;                                    \
    _Pragma("unroll")                                                          \
    for (int j = 0; j < 4; j++){                                               \
      int col = cb + j*64;                                                     \
      pb[j].x = pb[j].y = pb[j].z = pb[j].w = 0u;                              \
      if (col < 240) pb[j] = *(const uint4*)(Bt + col*416 + kgb);              \
    } }

  LOADB2(0);

  // ---- stage A panel: k<80 from h (f32->bf16), 80<=k<400 from agg, else 0
  {
    const int grow = row0 + ra;
    uint4 tA[NKT];
    #pragma unroll
    for (int c = 0; c < NKT; c++){
      int kg = c*32 + ka;
      uint4 pa; pa.x = pa.y = pa.z = pa.w = 0u;
      if (grow < NN){
        if (kg < 80){
          const float* ap = h + grow*80 + kg;
          float4 f0 = *(const float4*)ap;
          float4 f1 = *(const float4*)(ap + 4);
          pa.x = pk(f0.x, f0.y); pa.y = pk(f0.z, f0.w);
          pa.z = pk(f1.x, f1.y); pa.w = pk(f1.z, f1.w);
        } else if (kg - 80 < 320){
          pa = *(const uint4*)(agg + grow*320 + (kg - 80));
        }
      }
      tA[c] = pa;
    }
    #pragma unroll
    for (int c = 0; c < NKT; c++)
      ldsst16(&As[ra*AST + c*32 + ka], tA[c]);
  }
  __syncthreads();

  // ---- main K loop (r4 verbatim)
  #pragma unroll
  for (int ks = 0; ks < NKT; ks++){
    #pragma unroll
    for (int j = 0; j < 4; j++)
      ldsst16(&Bs[(cb + j*64)*44 + kb], pb[j]);
    __syncthreads();

    if (ks + 1 < NKT) LOADB2((ks + 1)*32);

    bf16x8 af[4], bfv[4];
    #pragma unroll
    for (int rt = 0; rt < 4; rt++)
      af[rt] = ldsld8(&As[(rt*16 + m16)*AST + ks*32 + q*8]);
    #pragma unroll
    for (int ct = 0; ct < 4; ct++)
      bfv[ct] = ldsld8(&Bs[(wc + ct*16 + m16)*44 + q*8]);
    #pragma unroll
    for (int rt = 0; rt < 4; rt++)
      #pragma unroll
      for (int ct = 0; ct < 4; ct++)
        acc[rt][ct] = __builtin_amdgcn_mfma_f32_16x16x32_bf16(af[rt], bfv[ct], acc[rt][ct], 0, 0, 0);
    __syncthreads();
  }
#undef LOADB2

  // ---- preload mini-GEMM B tile 0 (overlaps epilogue)
  uint4 pb1[4];
  if (Bt1n){
    #pragma unroll
    for (int j = 0; j < 4; j++){
      int col = cb + j*64;
      pb1[j].x = pb1[j].y = pb1[j].z = pb1[j].w = 0u;
      if (col < 160) pb1[j] = *(const uint4*)(Bt1n + col*96 + kb);
    }
  }

  // ---- epilogue: stage P|Q|R in eL
  #pragma unroll
  for (int rt = 0; rt < 4; rt++){
    #pragma unroll
    for (int ct = 0; ct < 4; ct++){
      int col = wc + ct*16 + m16;
      if (col >= 240) continue;
      #pragma unroll
      for (int rr = 0; rr < 4; rr++){
        int r = rt*16 + q*4 + rr;
        eL[r*248 + col] = f2b(acc[rt][ct][rr]);
      }
    }
  }
  __syncthreads();

  // ---- combine -> h_new; write global f32 + LDS bf16 panel
  #pragma unroll
  for (int i = 0; i < 20; i++){
    int idx = tid + i*256;
    int r = idx / 80, c = idx - r*80;
    int row = row0 + r;
    if (row < NN){
      float P = b2f(eL[r*248 + c]);
      float Q = b2f(eL[r*248 + 80 + c]);
      float R = b2f(eL[r*248 + 160 + c]);
      float o = P + scf[row]*Q + invf[row]*R + bias2v[c];
      float hn = hp[row*80 + c] + fmaxf(o, 0.f);
      hp[row*80 + c] = hn;
      if (Bt1n) hA[r*100 + c] = f2b(hn);
    } else if (Bt1n && idx < 64*80){
      hA[r*100 + c] = f2b(0.f);   // tail rows: defined values for mini-GEMM
    }
  }
  if (Bt1n){
    // zero pad k in [80,96)
    int r = tid >> 2, off = 80 + (tid & 3)*4;
    *(uint2*)&hA[r*100 + off] = make_uint2(0u, 0u);
  }
  __syncthreads();

  // ---- mini-GEMM: U = h_new @ Bt1[next] (K=96, 160 cols), write Ua/Ub
  if (Bt1n){
    f32x4 acc2[4][4] = {};
    #pragma unroll
    for (int ks = 0; ks < 3; ks++){
      #pragma unroll
      for (int j = 0; j < 4; j++)
        ldsst16(&Bs[(cb + j*64)*44 + kb], pb1[j]);
      __syncthreads();

      if (ks + 1 < 3){
        int kgb = (ks + 1)*32 + kb;
        #pragma unroll
        for (int j = 0; j < 4; j++){
          int col = cb + j*64;
          pb1[j].x = pb1[j].y = pb1[j].z = pb1[j].w = 0u;
          if (col < 160) pb1[j] = *(const uint4*)(Bt1n + col*96 + kgb);
        }
      }

      bf16x8 af[4], bfv[4];
      #pragma unroll
      for (int rt = 0; rt < 4; rt++)
        af[rt] = ldsld8((const short*)hA + (rt*16 + m16)*100 + ks*32 + q*8);
      #pragma unroll
      for (int ct = 0; ct < 4; ct++)
        bfv[ct] = ldsld8(&Bs[(wc + ct*16 + m16)*44 + q*8]);
      #pragma unroll
      for (int rt = 0; rt < 4; rt++)
        #pragma unroll
        for (int ct = 0; ct < 4; ct++)
          acc2[rt][ct] = __builtin_amdgcn_mfma_f32_16x16x32_bf16(af[rt], bfv[ct], acc2[rt][ct], 0, 0, 0);
      __syncthreads();
    }
    #pragma unroll
    for (int rt = 0; rt < 4; rt++){
      #pragma unroll
      for (int rr = 0; rr < 4; rr++){
        int row = row0 + rt*16 + q*4 + rr;
        if (row >= NN) continue;
        #pragma unroll
        for (int ct = 0; ct < 4; ct++){
          int col = wc + ct*16 + m16;
          if (col >= 160) continue;
          float v = acc2[rt][ct][rr] + bias1n[col];
          if (col < 80) Ua[row*80 + col]      = f2b(v);
          else          Ub[row*80 + col - 80] = f2b(v);
        }
      }
    }
  }
}

// ------------------------------------------------------------------ aggregation
// 3 nodes/wave: lane/20 = node slot, (lane%20)*4 = feature offset (uint2 = 4 bf16)
__global__ __launch_bounds__(256) void k_agg(const bf16* __restrict__ Ua,
                      const bf16* __restrict__ Ub,
                      const int* __restrict__ rowptr,
                      const int* __restrict__ colidx, bf16* __restrict__ agg)
{
  int lane = threadIdx.x & 63;
  int slot = lane / 20;
  int n = blockIdx.x*12 + (threadIdx.x >> 6)*3 + slot;
  if (slot >= 3 || n >= NN) return;
  int fo = (lane - slot*20) * 4;
  int rs = rowptr[n], re = rowptr[n+1];
  int deg = re - rs;

  float a[4];
  {
    uint2 ua = *(const uint2*)(Ua + n*80 + fo);
    a[0] = __uint_as_float(ua.x << 16);
    a[1] = __uint_as_float(ua.x & 0xffff0000u);
    a[2] = __uint_as_float(ua.y << 16);
    a[3] = __uint_as_float(ua.y & 0xffff0000u);
  }
  float sb[4] = {0.f,0.f,0.f,0.f}, sq[4] = {0.f,0.f,0.f,0.f};
  float mn[4] = {1e30f,1e30f,1e30f,1e30f}, mx[4] = {-1e30f,-1e30f,-1e30f,-1e30f};

#define ACC2(w, o) { \
    float b0 = __uint_as_float((w) << 16); \
    float b1 = __uint_as_float((w) & 0xffff0000u); \
    sb[o] += b0; sq[o] += b0*b0; mn[o] = fminf(mn[o],b0); mx[o] = fmaxf(mx[o],b0); \
    sb[o+1] += b1; sq[o+1] += b1*b1; mn[o+1] = fminf(mn[o+1],b1); mx[o+1] = fmaxf(mx[o+1],b1); }

  for (int e = rs; e < re; e += 8){
    int cnt = re - e; if (cnt > 8) cnt = 8;
    int s[8];
    #pragma unroll
    for (int j = 0; j < 8; j++) s[j] = (j < cnt) ? colidx[e + j] : s[0];
    uint2 u[8];
    #pragma unroll
    for (int j = 0; j < 8; j++) u[j] = *(const uint2*)(Ub + s[j]*80 + fo);
    #pragma unroll
    for (int j = 0; j < 8; j++){
      if (j < cnt){ ACC2(u[j].x, 0); ACC2(u[j].y, 2); }
    }
  }
#undef ACC2

  float degc = (float)(deg > 0 ? deg : 1);
  float inv = 1.f/degc;
  float dm = (float)deg;
  float mean0, mean1, v0, v1, sd0, sd1, lo0, lo1, hi0, hi1;

  mean0 = (dm*a[0] + sb[0])*inv; mean1 = (dm*a[1] + sb[1])*inv;
  v0 = (dm*a[0]*a[0] + 2.f*a[0]*sb[0] + sq[0])*inv - mean0*mean0;
  v1 = (dm*a[1]*a[1] + 2.f*a[1]*sb[1] + sq[1])*inv - mean1*mean1;
  sd0 = sqrtf(fmaxf(v0,0.f)+1e-5f); sd1 = sqrtf(fmaxf(v1,0.f)+1e-5f);
  lo0 = deg>0 ? a[0]+mn[0] : 0.f; lo1 = deg>0 ? a[1]+mn[1] : 0.f;
  hi0 = deg>0 ? a[0]+mx[0] : 0.f; hi1 = deg>0 ? a[1]+mx[1] : 0.f;
  unsigned o0 = pk(mean0, mean1);
  unsigned l0 = pk(lo0, lo1), h0 = pk(hi0, hi1), t0 = pk(sd0, sd1);

  mean0 = (dm*a[2] + sb[2])*inv; mean1 = (dm*a[3] + sb[3])*inv;
  v0 = (dm*a[2]*a[2] + 2.f*a[2]*sb[2] + sq[2])*inv - mean0*mean0;
  v1 = (dm*a[3]*a[3] + 2.f*a[3]*sb[3] + sq[3])*inv - mean1*mean1;
  sd0 = sqrtf(fmaxf(v0,0.f)+1e-5f); sd1 = sqrtf(fmaxf(v1,0.f)+1e-5f);
  lo0 = deg>0 ? a[2]+mn[2] : 0.f; lo1 = deg>0 ? a[3]+mn[3] : 0.f;
  hi0 = deg>0 ? a[2]+mx[2] : 0.f; hi1 = deg>0 ? a[3]+mx[3] : 0.f;
  unsigned o1 = pk(mean0, mean1);
  unsigned l1 = pk(lo0, lo1), h1 = pk(hi0, hi1), t1 = pk(sd0, sd1);

  bf16* ag = agg + n*320 + fo;
  *(uint2*)(ag)       = make_uint2(o0, o1);
  *(uint2*)(ag + 80)  = make_uint2(l0, l1);
  *(uint2*)(ag + 160) = make_uint2(h0, h1);
  *(uint2*)(ag + 240) = make_uint2(t0, t1);
}

// ------------------------------------------------------------------ fused mean-pool + head
__global__ __launch_bounds__(128) void k_poolmlp(const float* __restrict__ h,
                        const int* __restrict__ batch,
                        const void* __restrict__ mlpW, const void* __restrict__ mlpb,
                        const int* __restrict__ flag, void* __restrict__ outp){
  __shared__ float sred[128];
  __shared__ int sb[2];
  int g = blockIdx.x;
  int t = threadIdx.x;
  if (t < 2){
    int target = g + t;
    int lo = 0, hi = NN;
    while (lo < hi){ int mid = (lo + hi) >> 1; if (batch[mid] < target) lo = mid + 1; else hi = mid; }
    sb[t] = lo;
  }
  __syncthreads();
  int lo = sb[0], hi = sb[1];
  float s = 0.f;
  if (t < 80)
    for (int n = lo; n < hi; n++) s += h[n*80 + t];
  int fl = flag[0];
  float wv = (t < 80) ? rdw(mlpW, t, fl) : 0.f;
  sred[t] = s * wv;
  __syncthreads();
  for (int off = 64; off > 0; off >>= 1){
    if (t < off) sred[t] += sred[t + off];
    __syncthreads();
  }
  if (t == 0){
    float cnt = (float)(hi - lo); if (cnt < 1.f) cnt = 1.f;
    float r = sred[0]/cnt + rdw(mlpb, 0, fl);
    if (fl) ((float*)outp)[g] = r;
    else    ((bf16*)outp)[g] = f2b(r);
  }
}

// ------------------------------------------------------------------ launch
extern "C" void kernel_launch(void* const* d_in, const int* in_sizes, int n_in,
                              void* d_out, int out_size, void* d_ws, size_t ws_size,
                              hipStream_t stream)
{
  const int*  x     = (const int*) d_in[0];
  const int*  ei    = (const int*) d_in[1];
  const int*  batch = (const int*) d_in[2];
  const void* avgp  = d_in[3];
  const void* aemb  = d_in[4];
  const void* preW  = d_in[5];
  const void* preb  = d_in[6];
  const void* postW = d_in[7];
  const void* postb = d_in[8];
  const void* linW  = d_in[9];
  const void* linb  = d_in[10];
  const void* bng   = d_in[11];
  const void* bnb   = d_in[12];
  const void* bnm   = d_in[13];
  const void* bnv   = d_in[14];
  const void* mlpW  = d_in[15];
  const void* mlpb  = d_in[16];

  char* w = (char*)d_ws;
  int*   flag   = (int*)  (w + 400000);       //       256  (zeroed)
  int*   rowptr = (int*)  (w + 401280);       //   200,064
  int*   colidx = (int*)  (w + 601344);       // 3,200,000
  float* scf    = (float*)(w + 3801344);      //   200,000
  float* invf   = (float*)(w + 4001344);      //   200,000
  float* bias1  = (float*)(w + 4201344);      //     2,560
  float* bias2  = (float*)(w + 4203904);      //     1,280
  bf16*  Btl    = (bf16*) (w + 4205184);      //    61,440
  bf16*  Bt1    = (bf16*) (w + 4266624);      //   122,880
  bf16*  Bt2    = (bf16*) (w + 4389504);      //   798,720
  float* h      = (float*)(w + 5188224);      // 16,000,000  f32 [N,80]
  bf16*  Ua     = (bf16*) (w + 21188224);     //  8,000,000  bf16 [N,80]
  bf16*  Ub     = (bf16*) (w + 29188224);     //  8,000,000  bf16 [N,80]
  bf16*  agg    = (bf16*) (w + 45188224);     // 32,000,000  bf16 [N,320]
  // pre-loop overlays inside the agg region:
  bf16*  pwb    = (bf16*) (w + 45188224);     //   665,600
  float* Wf     = (float*)(w + 45853824);     // 1,331,200
  int* staging  = (int*)  (w + 47185024);     // 3,200,000
  int* chunkcnt = (int*)  (w + 50385024);     //   613,088  [NCH][NBUCK]
  int* btotal   = (int*)  (w + 52831120);     //     3,128
  int* bbase    = (int*)  (w + 52834248);     //     3,136  (NBUCK+1)
  // total 77,188,224 B

  k_zero <<<1, 256, 0, stream>>>(flag, 64);
  k_probe<<<16, 256, 0, stream>>>(aemb, flag);

  // atomic-free CSR build
  k_hist <<<NCH, 256, 0, stream>>>(ei, chunkcnt);
  k_cscan<<<NBUCK, 256, 0, stream>>>(chunkcnt, btotal);
  k_bscan<<<1, 256, 0, stream>>>(btotal, bbase);
  k_place<<<NCH, 256, 0, stream>>>(ei, chunkcnt, bbase, staging);

  k_prep_all<<<1662, 256, 0, stream>>>(preW, preb, postW, postb, linW, linb,
                                       bng, bnb, bnm, bnv, flag,
                                       pwb, Btl, Bt1, bias1, bias2);

  // Wf[i] = postW[i](bf16) @ Btl[i]^T   (f32 out)
  k_mgemm<0,1,96,100><<<dim3(17,1,4), 256, 0, stream>>>(
      pwb, 80, 80, nullptr, 0, 0,
      Btl, 96, 80, nullptr, Wf, nullptr, 80, 1040,
      166400, 15360, 332800);
  k_prep_Bt2<<<(4*240*416 + 255)/256, 256, 0, stream>>>(Wf, Bt2);

  k_atom <<<(NN*10 + 255)/256, 256, 0, stream>>>(x, aemb, flag, h);

  // fused rowptr/scf/invf + counting-sorted colidx
  k_csr<<<NBUCK, 256, 0, stream>>>(staging, bbase, avgp, flag, rowptr, scf, invf, colidx);

  const int gx = (NN + 63)/64;   // 782
  // layer-0 GEMM1 (subsequent layers' GEMM1 are fused into k_g2's tail)
  k_mgemm<1,2,96,100><<<dim3(gx,1,1), 256, 0, stream>>>(
      h, 80, 80, nullptr, 0, 0,
      Bt1, 96, 160, bias1, Ua, Ub, 0, NN,
      0, 0, 0);
  for (int i = 0; i < 4; i++){
    k_agg<<<(NN + 11)/12, 256, 0, stream>>>(Ua, Ub, rowptr, colidx, agg);
    const bf16* nBt1   = (i < 3) ? (Bt1 + (i+1)*15360) : nullptr;
    const float* nb1   = (i < 3) ? (bias1 + (i+1)*160) : bias1;
    k_g2<<<dim3(gx,1,1), 256, 0, stream>>>(
        h, agg, Bt2 + i*99840, bias2 + i*80, scf, invf, h,
        nBt1, nb1, Ua, Ub);
  }

  k_poolmlp<<<NGR, 128, 0, stream>>>(h, batch, mlpW, mlpb, flag, d_out);
}

// Round 11
// 573.904 us; speedup vs baseline: 1.2658x; 1.0224x over previous
//
#include <hip/hip_runtime.h>
#include <hip/hip_bf16.h>

#define NN 50000
#define NE 800000
#define FD 80
#define NGR 1024
#define NF 9

// bucketed CSR sort (atomic-free counting sort)
#define BSH 6
#define NBUCK ((NN + 63) >> 6)     // 782 node-buckets of 64
#define CSH 12
#define NCH ((NE + 4095) >> 12)    // 196 edge-chunks of 4096
#define BCAP 2048

using bf16 = __hip_bfloat16;
typedef __attribute__((ext_vector_type(8))) short bf16x8;
typedef __attribute__((ext_vector_type(4))) float f32x4;

static __device__ __forceinline__ float b2f(bf16 v){ return __bfloat162float(v); }
static __device__ __forceinline__ bf16 f2b(float v){ return __float2bfloat16(v); }
static __device__ __forceinline__ float rdw(const void* p, int i, int fl){
  return fl ? ((const float*)p)[i] : b2f(((const bf16*)p)[i]);
}
static __device__ __forceinline__ unsigned pk(float a, float b){
  bf16 x = f2b(a), y = f2b(b);
  return (unsigned)*(unsigned short*)&x | ((unsigned)*(unsigned short*)&y << 16);
}
// 8B-granule LDS access (strides are 8B- but not 16B-aligned)
static __device__ __forceinline__ bf16x8 ldsld8(const short* p){
  union { bf16x8 v; uint2 u[2]; } r;
  r.u[0] = *(const uint2*)(p);
  r.u[1] = *(const uint2*)(p + 4);
  return r.v;
}
static __device__ __forceinline__ void ldsst16(short* p, uint4 v){
  *(uint2*)(p)     = make_uint2(v.x, v.y);
  *(uint2*)(p + 4) = make_uint2(v.z, v.w);
}

// ------------------------------------------------------------------ utility
__global__ void k_zero(int* __restrict__ p, int n){
  int t = blockIdx.x*256 + threadIdx.x;
  if (t < n) p[t] = 0;
}

__global__ void k_probe(const void* __restrict__ emb, int* __restrict__ flag){
  int t = blockIdx.x*256 + threadIdx.x;
  float v = b2f(((const bf16*)emb)[t]);
  if (!(fabsf(v) < 1e4f)) atomicOr(flag, 1);
}

// ------------------------------------------------------------------ fused weight prep
__global__ __launch_bounds__(256) void k_prep_all(
    const void* __restrict__ preW, const void* __restrict__ preb,
    const void* __restrict__ postW, const void* __restrict__ postb,
    const void* __restrict__ linW, const void* __restrict__ linb,
    const void* __restrict__ bng, const void* __restrict__ bnb,
    const void* __restrict__ bnm, const void* __restrict__ bnv,
    const int* __restrict__ flag,
    bf16* __restrict__ pwb, bf16* __restrict__ Btl, bf16* __restrict__ Bt1,
    float* __restrict__ bias1, float* __restrict__ bias2)
{
  int fl = flag[0];
  int b = blockIdx.x;
  if (b < 1300){
    int t = b*256 + threadIdx.x;
    pwb[t] = f2b(rdw(postW, t, fl));
  } else if (b < 1420){
    int t = (b - 1300)*256 + threadIdx.x;
    int j = t % 96, c = (t/96) % 80, i = t/(96*80);
    float v = 0.f;
    if (j < 80){
      float gs = rdw(bng, i*80 + c, fl) * rsqrtf(rdw(bnv, i*80 + c, fl) + 1e-5f);
      v = rdw(linW, i*6400 + j*80 + c, fl) * gs;
    }
    Btl[t] = f2b(v);
  } else if (b < 1660){
    int t = (b - 1420)*256 + threadIdx.x;
    int k = t % 96, c = (t/96) % 160, i = t/(96*160);
    float v = 0.f;
    if (k < 80)
      v = (c < 80) ? rdw(preW, (i*160 + k)*80 + c, fl)
                   : rdw(preW, (i*160 + 80 + k)*80 + (c - 80), fl);
    Bt1[t] = f2b(v);
    if (k == 0) bias1[i*160 + c] = (c < 80) ? rdw(preb, i*80 + c, fl) : 0.f;
  } else {
    int t = (b - 1660)*256 + threadIdx.x;
    if (t >= 4*80) return;
    int i = t / 80, f = t - i*80;
    float s = 0.f;
    for (int j = 0; j < 80; j++)
      s += rdw(postb, i*80 + j, fl) * rdw(linW, (i*80 + j)*80 + f, fl);
    s += rdw(linb, t, fl);
    float gs = rdw(bng, t, fl) * rsqrtf(rdw(bnv, t, fl) + 1e-5f);
    bias2[t] = (s - rdw(bnm, t, fl)) * gs + rdw(bnb, t, fl);
  }
}

// Bt2[i][c][k] (c<240 cols, 416-k) from Wf (f32 [i][1040][80]).
__global__ void k_prep_Bt2(const float* __restrict__ Wf, bf16* __restrict__ Bt2){
  int t = blockIdx.x*256 + threadIdx.x;
  if (t >= 4*240*416) return;
  int k = t % 416;
  int c = (t/416) % 240;
  int i = t/(416*240);
  float v = 0.f;
  if (k < 400){
    int blk = c/80, f = c - blk*80;
    if (blk == 0) v = Wf[(i*1040 + k)*80 + f];
    else if (k >= 80){
      int row = (blk == 1 ? 400 : 720) + (k - 80);
      v = Wf[(i*1040 + row)*80 + f];
    }
  }
  Bt2[t] = f2b(v);
}

// ------------------------------------------------------------------ graph prep
// Vectorized: one thread per (node, 8-feature block); 9 x 16B gathers + float4
// stores. Summation order (c ascending) identical to the scalar version.
__global__ void k_atom(const int* __restrict__ x, const void* __restrict__ emb,
                       const int* __restrict__ flag, float* __restrict__ h){
  int fl = flag[0];
  int gid = blockIdx.x*256 + threadIdx.x;
  if (gid >= NN*10) return;
  int n = gid / 10, fb = gid - n*10;
  int f0 = fb*8;
  int xr[NF];
  #pragma unroll
  for (int c = 0; c < NF; c++) xr[c] = x[n*NF + c];
  float s[8] = {0.f,0.f,0.f,0.f,0.f,0.f,0.f,0.f};
  if (fl){
    #pragma unroll
    for (int c = 0; c < NF; c++){
      const float* ep = (const float*)emb + (c*119 + xr[c])*80 + f0;
      float4 a = *(const float4*)ep, b = *(const float4*)(ep + 4);
      s[0]+=a.x; s[1]+=a.y; s[2]+=a.z; s[3]+=a.w;
      s[4]+=b.x; s[5]+=b.y; s[6]+=b.z; s[7]+=b.w;
    }
  } else {
    #pragma unroll
    for (int c = 0; c < NF; c++){
      const bf16* ep = (const bf16*)emb + (c*119 + xr[c])*80 + f0;
      uint4 u = *(const uint4*)ep;
      s[0]+=__uint_as_float(u.x<<16); s[1]+=__uint_as_float(u.x&0xffff0000u);
      s[2]+=__uint_as_float(u.y<<16); s[3]+=__uint_as_float(u.y&0xffff0000u);
      s[4]+=__uint_as_float(u.z<<16); s[5]+=__uint_as_float(u.z&0xffff0000u);
      s[6]+=__uint_as_float(u.w<<16); s[7]+=__uint_as_float(u.w&0xffff0000u);
    }
  }
  float* hp = h + n*80 + f0;
  *(float4*)hp       = make_float4(s[0],s[1],s[2],s[3]);
  *(float4*)(hp + 4) = make_float4(s[4],s[5],s[6],s[7]);
}

// ---- atomic-free CSR build: hist -> cscan -> bscan -> place -> csr ----

// Per-chunk bucket histogram (coalesced matrix write). 4096 edges/chunk.
__global__ __launch_bounds__(256) void k_hist(const int* __restrict__ ei,
                                              int* __restrict__ chunkcnt){
  __shared__ int hist[NBUCK];
  int c = blockIdx.x, t = threadIdx.x;
  for (int i = t; i < NBUCK; i += 256) hist[i] = 0;
  __syncthreads();
  #pragma unroll
  for (int j = 0; j < 16; j++){
    int e = (c << CSH) + j*256 + t;
    if (e < NE) atomicAdd(&hist[ei[NE + e] >> BSH], 1);
  }
  __syncthreads();
  for (int i = t; i < NBUCK; i += 256) chunkcnt[c*NBUCK + i] = hist[i];
}

// Per-bucket exclusive scan over chunks (in-place) + bucket totals.
__global__ __launch_bounds__(256) void k_cscan(int* __restrict__ chunkcnt,
                                               int* __restrict__ btotal){
  __shared__ int buf[256];
  int b = blockIdx.x, t = threadIdx.x;
  int v[4]; int s = 0;
  #pragma unroll
  for (int j = 0; j < 4; j++){
    int c = t*4 + j;
    v[j] = (c < NCH) ? chunkcnt[c*NBUCK + b] : 0;
    s += v[j];
  }
  buf[t] = s;
  __syncthreads();
  for (int off = 1; off < 256; off <<= 1){
    int xv = (t >= off) ? buf[t - off] : 0;
    __syncthreads();
    buf[t] += xv;
    __syncthreads();
  }
  int excl = buf[t] - s;
  #pragma unroll
  for (int j = 0; j < 4; j++){
    int c = t*4 + j;
    if (c < NCH){ chunkcnt[c*NBUCK + b] = excl; excl += v[j]; }
  }
  if (t == 255) btotal[b] = buf[255];
}

// Exclusive scan of bucket totals -> bucket base offsets (bbase[NBUCK] = NE).
__global__ __launch_bounds__(256) void k_bscan(const int* __restrict__ btotal,
                                               int* __restrict__ bbase){
  __shared__ int buf[256];
  int t = threadIdx.x;
  int v[4]; int s = 0;
  #pragma unroll
  for (int j = 0; j < 4; j++){
    int c = t*4 + j;
    v[j] = (c < NBUCK) ? btotal[c] : 0;
    s += v[j];
  }
  buf[t] = s;
  __syncthreads();
  for (int off = 1; off < 256; off <<= 1){
    int xv = (t >= off) ? buf[t - off] : 0;
    __syncthreads();
    buf[t] += xv;
    __syncthreads();
  }
  int excl = buf[t] - s;
  #pragma unroll
  for (int j = 0; j < 4; j++){
    int c = t*4 + j;
    if (c < NBUCK){ bbase[c] = excl; excl += v[j]; }
  }
  if (t == 255) bbase[NBUCK] = buf[255];
}

// Place each edge into its bucket's staging range; rank via LDS atomics.
__global__ __launch_bounds__(256) void k_place(const int* __restrict__ ei,
                        const int* __restrict__ chunkcnt, const int* __restrict__ bbase,
                        int* __restrict__ staging){
  __shared__ int basep[NBUCK];
  __shared__ int cur[NBUCK];
  int c = blockIdx.x, t = threadIdx.x;
  for (int i = t; i < NBUCK; i += 256){
    basep[i] = chunkcnt[c*NBUCK + i] + bbase[i];
    cur[i] = 0;
  }
  __syncthreads();
  #pragma unroll
  for (int j = 0; j < 16; j++){
    int e = (c << CSH) + j*256 + t;
    if (e < NE){
      int d = ei[NE + e], s = ei[e];
      int b = d >> BSH;
      int r = atomicAdd(&cur[b], 1);
      staging[basep[b] + r] = (s << BSH) | (d & 63);
    }
  }
}

// Fused per-bucket finalize: node counts -> rowptr/scf/invf + counting sort
// into colidx (sequential reads, coalesced writes).
__global__ __launch_bounds__(256) void k_csr(const int* __restrict__ staging,
                        const int* __restrict__ bbase, const void* __restrict__ avgp,
                        const int* __restrict__ flag, int* __restrict__ rowptr,
                        float* __restrict__ scf, float* __restrict__ invf,
                        int* __restrict__ colidx){
  __shared__ int lcnt[64], lrp[64], lcur[64];
  __shared__ int colbuf[BCAP];
  int b = blockIdx.x, t = threadIdx.x;
  int base = bbase[b];
  int cnt  = bbase[b+1] - base;
  if (t < 64){ lcnt[t] = 0; lcur[t] = 0; }
  __syncthreads();
  for (int i = t; i < cnt; i += 256)
    atomicAdd(&lcnt[staging[base + i] & 63], 1);
  __syncthreads();
  if (t < 64) lrp[t] = lcnt[t];
  __syncthreads();
  for (int off = 1; off < 64; off <<= 1){
    int xv = (t < 64 && t >= off) ? lrp[t - off] : 0;
    __syncthreads();
    if (t < 64) lrp[t] += xv;
    __syncthreads();
  }
  int n0 = b << BSH;
  if (t < 64){
    int ex = lrp[t] - lcnt[t];
    lrp[t] = ex;
    int n = n0 + t;
    if (n < NN){
      rowptr[n] = base + ex;
      float degc = (float)(lcnt[t] > 0 ? lcnt[t] : 1);
      float logd = logf(degc + 1.f);
      float avg = rdw(avgp, 0, flag[0]);
      scf[n] = logd / avg;
      invf[n] = avg / logd;
    }
  }
  if (b == 0 && t == 0) rowptr[NN] = NE;
  __syncthreads();
  if (cnt <= BCAP){
    for (int i = t; i < cnt; i += 256){
      int v = staging[base + i];
      int l = v & 63;
      int pos = lrp[l] + atomicAdd(&lcur[l], 1);
      colbuf[pos] = v >> BSH;
    }
    __syncthreads();
    for (int i = t; i < cnt; i += 256)
      colidx[base + i] = colbuf[i];
  } else {
    for (int i = t; i < cnt; i += 256){
      int v = staging[base + i];
      int l = v & 63;
      int pos = lrp[l] + atomicAdd(&lcur[l], 1);
      colidx[base + pos] = v >> BSH;
    }
  }
}

// ------------------------------------------------------------------ MFMA GEMM (r4 structure, best measured)
// 64-row x 256-col block tile, 4 waves. Full A-panel staged to LDS up-front,
// K-loop streams B via reg->LDS with prefetch. Used for Wf (OUTMODE1) and
// layer-0 GEMM1 (OUTMODE2).
template<int AF32, int OUTMODE, int K_, int AST>
__global__ __launch_bounds__(256) void k_mgemm(
    const void* __restrict__ A1p, int s1, int KA,
    const bf16* __restrict__ A2, int s2, int KB,
    const bf16* __restrict__ Btp, int Bts, int Ncols,
    const float* __restrict__ bias,
    void* __restrict__ Cbase, void* __restrict__ Cp2, int Cstride, int M,
    int lA1b, int lBtb, int lCb)
{
  const void* A1 = (const char*)A1p + (size_t)blockIdx.z*lA1b;
  const bf16* Bt = (const bf16*)((const char*)Btp + (size_t)blockIdx.z*lBtb);
  void* Cp = (char*)Cbase + (size_t)blockIdx.z*lCb;

  constexpr int NKT = K_ / 32;
  __shared__ short As[64*AST];
  __shared__ short Bs[256*44];

  const int tid = threadIdx.x;
  const int row0 = blockIdx.x * 64;
  const int wave = tid >> 6, lane = tid & 63;
  const int wc = wave * 64;
  const int m16 = lane & 15, q = lane >> 4;

  const int ra = tid >> 2, ka = (tid & 3) * 8;
  const int cb = tid >> 2, kb = (tid & 3) * 8;

  f32x4 acc[4][4] = {};
  uint4 pb[4];

#define LOADB(k0_) { int kgb = (k0_) + kb;                                     \
    _Pragma("unroll")                                                          \
    for (int j = 0; j < 4; j++){                                               \
      int col = cb + j*64;                                                     \
      pb[j].x = pb[j].y = pb[j].z = pb[j].w = 0u;                              \
      if (col < Ncols) pb[j] = *(const uint4*)(Bt + col*Bts + kgb);            \
    } }

  LOADB(0);

  {
    const int grow = row0 + ra;
    uint4 tA[NKT];
    #pragma unroll
    for (int c = 0; c < NKT; c++){
      int kg = c*32 + ka;
      uint4 pa; pa.x = pa.y = pa.z = pa.w = 0u;
      if (grow < M){
        if (kg < KA){
          if (AF32){
            const float* ap = (const float*)A1 + grow*s1 + kg;
            float4 f0 = *(const float4*)ap;
            float4 f1 = *(const float4*)(ap + 4);
            pa.x = pk(f0.x, f0.y); pa.y = pk(f0.z, f0.w);
            pa.z = pk(f1.x, f1.y); pa.w = pk(f1.z, f1.w);
          } else {
            pa = *(const uint4*)((const bf16*)A1 + grow*s1 + kg);
          }
        } else if (kg - KA < KB){
          pa = *(const uint4*)(A2 + grow*s2 + (kg - KA));
        }
      }
      tA[c] = pa;
    }
    #pragma unroll
    for (int c = 0; c < NKT; c++)
      ldsst16(&As[ra*AST + c*32 + ka], tA[c]);
  }
  __syncthreads();

  #pragma unroll
  for (int ks = 0; ks < NKT; ks++){
    #pragma unroll
    for (int j = 0; j < 4; j++)
      ldsst16(&Bs[(cb + j*64)*44 + kb], pb[j]);
    __syncthreads();

    if (ks + 1 < NKT) LOADB((ks + 1)*32);

    bf16x8 af[4], bfv[4];
    #pragma unroll
    for (int rt = 0; rt < 4; rt++)
      af[rt] = ldsld8(&As[(rt*16 + m16)*AST + ks*32 + q*8]);
    #pragma unroll
    for (int ct = 0; ct < 4; ct++)
      bfv[ct] = ldsld8(&Bs[(wc + ct*16 + m16)*44 + q*8]);
    #pragma unroll
    for (int rt = 0; rt < 4; rt++)
      #pragma unroll
      for (int ct = 0; ct < 4; ct++)
        acc[rt][ct] = __builtin_amdgcn_mfma_f32_16x16x32_bf16(af[rt], bfv[ct], acc[rt][ct], 0, 0, 0);
    __syncthreads();
  }
#undef LOADB

  #pragma unroll
  for (int rt = 0; rt < 4; rt++){
    #pragma unroll
    for (int rr = 0; rr < 4; rr++){
      int row = row0 + rt*16 + q*4 + rr;
      if (row >= M) continue;
      #pragma unroll
      for (int ct = 0; ct < 4; ct++){
        int col = wc + ct*16 + m16;
        if (col >= Ncols) continue;
        float v = acc[rt][ct][rr] + (bias ? bias[col] : 0.f);
        if (OUTMODE == 1) ((float*)Cp)[row*Cstride + col] = v;
        else {
          if (col < 80) ((bf16*)Cp )[row*80 + col]      = f2b(v);
          else          ((bf16*)Cp2)[row*80 + col - 80] = f2b(v);
        }
      }
    }
  }
}

// ------------------------------------------------------------------ GEMM2 + fused next-layer GEMM1, 32-ROW TILE
// r8/r10's k_g2 retiled 64->32 rows: As(32x420)+Bs = 49,408 B -> 3 blocks/CU
// (was 2), 12 waves/CU for latency hiding (round-10 evidence: k_g2 at 855 GB/s
// effective with every pipe idle = latency-bound at 8 waves/CU).
// A-stage: 8 threads/row, 7 chunk-iters of stride 64 shorts.
__global__ __launch_bounds__(256) void k_g2(
    const float* __restrict__ h, const bf16* __restrict__ agg,
    const bf16* __restrict__ Bt, const float* __restrict__ bias2v,
    const float* __restrict__ scf, const float* __restrict__ invf,
    float* __restrict__ hp,
    const bf16* __restrict__ Bt1n, const float* __restrict__ bias1n,
    bf16* __restrict__ Ua, bf16* __restrict__ Ub)
{
  constexpr int AST = 420, NKT = 13;
  __shared__ short As[32*AST];   // 26,880 B
  __shared__ short Bs[256*44];   // 22,528 B (total 49,408 -> 3 blocks/CU)
  bf16* eL = (bf16*)As;                 // epilogue staging 32x248 (15,872 B)
  bf16* hA = (bf16*)(As + 8192);        // h_new panel 32x100 (bytes 16,384..22,784)

  const int tid = threadIdx.x;
  const int row0 = blockIdx.x * 32;
  const int wave = tid >> 6, lane = tid & 63;
  const int wc = wave * 64;
  const int m16 = lane & 15, q = lane >> 4;
  const int ra = tid >> 3;           // 32 rows, 8 threads/row
  const int ka0 = (tid & 7) * 8;     // chunk start; stride 64 shorts
  const int cb = tid >> 2, kb = (tid & 3) * 8;

  f32x4 acc[2][4] = {};
  uint4 pb[4];

#define LOADB2(k0_) { int kgb = (k0_) + kb;                                    \
    _Pragma("unroll")                                                          \
    for (int j = 0; j < 4; j++){                                               \
      int col = cb + j*64;                                                     \
      pb[j].x = pb[j].y = pb[j].z = pb[j].w = 0u;                              \
      if (col < 240) pb[j] = *(const uint4*)(Bt + col*416 + kgb);              \
    } }

  LOADB2(0);

  // ---- stage A panel: k<80 from h (f32->bf16), 80<=k<400 from agg, else 0
  {
    const int grow = row0 + ra;
    uint4 tA[7];
    #pragma unroll
    for (int c = 0; c < 7; c++){
      int kg = ka0 + c*64;
      uint4 pa; pa.x = pa.y = pa.z = pa.w = 0u;
      if (kg < 416 && grow < NN){
        if (kg < 80){
          const float* ap = h + grow*80 + kg;
          float4 f0 = *(const float4*)ap;
          float4 f1 = *(const float4*)(ap + 4);
          pa.x = pk(f0.x, f0.y); pa.y = pk(f0.z, f0.w);
          pa.z = pk(f1.x, f1.y); pa.w = pk(f1.z, f1.w);
        } else if (kg < 400){
          pa = *(const uint4*)(agg + grow*320 + (kg - 80));
        }
      }
      tA[c] = pa;
    }
    #pragma unroll
    for (int c = 0; c < 7; c++){
      int kg = ka0 + c*64;
      if (kg < 416) ldsst16(&As[ra*AST + kg], tA[c]);
    }
  }
  __syncthreads();

  // ---- main K loop (r4 structure, 2 row-tiles)
  #pragma unroll
  for (int ks = 0; ks < NKT; ks++){
    #pragma unroll
    for (int j = 0; j < 4; j++)
      ldsst16(&Bs[(cb + j*64)*44 + kb], pb[j]);
    __syncthreads();

    if (ks + 1 < NKT) LOADB2((ks + 1)*32);

    bf16x8 af[2], bfv[4];
    #pragma unroll
    for (int rt = 0; rt < 2; rt++)
      af[rt] = ldsld8(&As[(rt*16 + m16)*AST + ks*32 + q*8]);
    #pragma unroll
    for (int ct = 0; ct < 4; ct++)
      bfv[ct] = ldsld8(&Bs[(wc + ct*16 + m16)*44 + q*8]);
    #pragma unroll
    for (int rt = 0; rt < 2; rt++)
      #pragma unroll
      for (int ct = 0; ct < 4; ct++)
        acc[rt][ct] = __builtin_amdgcn_mfma_f32_16x16x32_bf16(af[rt], bfv[ct], acc[rt][ct], 0, 0, 0);
    __syncthreads();
  }
#undef LOADB2

  // ---- preload mini-GEMM B tile 0 (overlaps epilogue)
  uint4 pb1[4];
  if (Bt1n){
    #pragma unroll
    for (int j = 0; j < 4; j++){
      int col = cb + j*64;
      pb1[j].x = pb1[j].y = pb1[j].z = pb1[j].w = 0u;
      if (col < 160) pb1[j] = *(const uint4*)(Bt1n + col*96 + kb);
    }
  }

  // ---- epilogue: stage P|Q|R in eL
  #pragma unroll
  for (int rt = 0; rt < 2; rt++){
    #pragma unroll
    for (int ct = 0; ct < 4; ct++){
      int col = wc + ct*16 + m16;
      if (col >= 240) continue;
      #pragma unroll
      for (int rr = 0; rr < 4; rr++){
        int r = rt*16 + q*4 + rr;
        eL[r*248 + col] = f2b(acc[rt][ct][rr]);
      }
    }
  }
  __syncthreads();

  // ---- combine -> h_new; write global f32 + LDS bf16 panel
  #pragma unroll
  for (int i = 0; i < 10; i++){
    int idx = tid + i*256;
    int r = idx / 80, c = idx - r*80;
    int row = row0 + r;
    if (row < NN){
      float P = b2f(eL[r*248 + c]);
      float Q = b2f(eL[r*248 + 80 + c]);
      float R = b2f(eL[r*248 + 160 + c]);
      float o = P + scf[row]*Q + invf[row]*R + bias2v[c];
      float hn = hp[row*80 + c] + fmaxf(o, 0.f);
      hp[row*80 + c] = hn;
      if (Bt1n) hA[r*100 + c] = f2b(hn);
    } else if (Bt1n && idx < 32*80){
      hA[r*100 + c] = f2b(0.f);   // tail rows: defined values for mini-GEMM
    }
  }
  if (Bt1n && tid < 128){
    // zero pad k in [80,96)
    int r = tid >> 2, off = 80 + (tid & 3)*4;
    *(uint2*)&hA[r*100 + off] = make_uint2(0u, 0u);
  }
  __syncthreads();

  // ---- mini-GEMM: U = h_new @ Bt1[next] (K=96, 160 cols), write Ua/Ub
  if (Bt1n){
    f32x4 acc2[2][4] = {};
    #pragma unroll
    for (int ks = 0; ks < 3; ks++){
      #pragma unroll
      for (int j = 0; j < 4; j++)
        ldsst16(&Bs[(cb + j*64)*44 + kb], pb1[j]);
      __syncthreads();

      if (ks + 1 < 3){
        int kgb = (ks + 1)*32 + kb;
        #pragma unroll
        for (int j = 0; j < 4; j++){
          int col = cb + j*64;
          pb1[j].x = pb1[j].y = pb1[j].z = pb1[j].w = 0u;
          if (col < 160) pb1[j] = *(const uint4*)(Bt1n + col*96 + kgb);
        }
      }

      bf16x8 af[2], bfv[4];
      #pragma unroll
      for (int rt = 0; rt < 2; rt++)
        af[rt] = ldsld8((const short*)hA + (rt*16 + m16)*100 + ks*32 + q*8);
      #pragma unroll
      for (int ct = 0; ct < 4; ct++)
        bfv[ct] = ldsld8(&Bs[(wc + ct*16 + m16)*44 + q*8]);
      #pragma unroll
      for (int rt = 0; rt < 2; rt++)
        #pragma unroll
        for (int ct = 0; ct < 4; ct++)
          acc2[rt][ct] = __builtin_amdgcn_mfma_f32_16x16x32_bf16(af[rt], bfv[ct], acc2[rt][ct], 0, 0, 0);
      __syncthreads();
    }
    #pragma unroll
    for (int rt = 0; rt < 2; rt++){
      #pragma unroll
      for (int rr = 0; rr < 4; rr++){
        int row = row0 + rt*16 + q*4 + rr;
        if (row >= NN) continue;
        #pragma unroll
        for (int ct = 0; ct < 4; ct++){
          int col = wc + ct*16 + m16;
          if (col >= 160) continue;
          float v = acc2[rt][ct][rr] + bias1n[col];
          if (col < 80) Ua[row*80 + col]      = f2b(v);
          else          Ub[row*80 + col - 80] = f2b(v);
        }
      }
    }
  }
}

// ------------------------------------------------------------------ aggregation
// 3 nodes/wave: lane/20 = node slot, (lane%20)*4 = feature offset (uint2 = 4 bf16)
__global__ __launch_bounds__(256) void k_agg(const bf16* __restrict__ Ua,
                      const bf16* __restrict__ Ub,
                      const int* __restrict__ rowptr,
                      const int* __restrict__ colidx, bf16* __restrict__ agg)
{
  int lane = threadIdx.x & 63;
  int slot = lane / 20;
  int n = blockIdx.x*12 + (threadIdx.x >> 6)*3 + slot;
  if (slot >= 3 || n >= NN) return;
  int fo = (lane - slot*20) * 4;
  int rs = rowptr[n], re = rowptr[n+1];
  int deg = re - rs;

  float a[4];
  {
    uint2 ua = *(const uint2*)(Ua + n*80 + fo);
    a[0] = __uint_as_float(ua.x << 16);
    a[1] = __uint_as_float(ua.x & 0xffff0000u);
    a[2] = __uint_as_float(ua.y << 16);
    a[3] = __uint_as_float(ua.y & 0xffff0000u);
  }
  float sb[4] = {0.f,0.f,0.f,0.f}, sq[4] = {0.f,0.f,0.f,0.f};
  float mn[4] = {1e30f,1e30f,1e30f,1e30f}, mx[4] = {-1e30f,-1e30f,-1e30f,-1e30f};

#define ACC2(w, o) { \
    float b0 = __uint_as_float((w) << 16); \
    float b1 = __uint_as_float((w) & 0xffff0000u); \
    sb[o] += b0; sq[o] += b0*b0; mn[o] = fminf(mn[o],b0); mx[o] = fmaxf(mx[o],b0); \
    sb[o+1] += b1; sq[o+1] += b1*b1; mn[o+1] = fminf(mn[o+1],b1); mx[o+1] = fmaxf(mx[o+1],b1); }

  for (int e = rs; e < re; e += 8){
    int cnt = re - e; if (cnt > 8) cnt = 8;
    int s[8];
    #pragma unroll
    for (int j = 0; j < 8; j++) s[j] = (j < cnt) ? colidx[e + j] : s[0];
    uint2 u[8];
    #pragma unroll
    for (int j = 0; j < 8; j++) u[j] = *(const uint2*)(Ub + s[j]*80 + fo);
    #pragma unroll
    for (int j = 0; j < 8; j++){
      if (j < cnt){ ACC2(u[j].x, 0); ACC2(u[j].y, 2); }
    }
  }
#undef ACC2

  float degc = (float)(deg > 0 ? deg : 1);
  float inv = 1.f/degc;
  float dm = (float)deg;
  float mean0, mean1, v0, v1, sd0, sd1, lo0, lo1, hi0, hi1;

  mean0 = (dm*a[0] + sb[0])*inv; mean1 = (dm*a[1] + sb[1])*inv;
  v0 = (dm*a[0]*a[0] + 2.f*a[0]*sb[0] + sq[0])*inv - mean0*mean0;
  v1 = (dm*a[1]*a[1] + 2.f*a[1]*sb[1] + sq[1])*inv - mean1*mean1;
  sd0 = sqrtf(fmaxf(v0,0.f)+1e-5f); sd1 = sqrtf(fmaxf(v1,0.f)+1e-5f);
  lo0 = deg>0 ? a[0]+mn[0] : 0.f; lo1 = deg>0 ? a[1]+mn[1] : 0.f;
  hi0 = deg>0 ? a[0]+mx[0] : 0.f; hi1 = deg>0 ? a[1]+mx[1] : 0.f;
  unsigned o0 = pk(mean0, mean1);
  unsigned l0 = pk(lo0, lo1), h0 = pk(hi0, hi1), t0 = pk(sd0, sd1);

  mean0 = (dm*a[2] + sb[2])*inv; mean1 = (dm*a[3] + sb[3])*inv;
  v0 = (dm*a[2]*a[2] + 2.f*a[2]*sb[2] + sq[2])*inv - mean0*mean0;
  v1 = (dm*a[3]*a[3] + 2.f*a[3]*sb[3] + sq[3])*inv - mean1*mean1;
  sd0 = sqrtf(fmaxf(v0,0.f)+1e-5f); sd1 = sqrtf(fmaxf(v1,0.f)+1e-5f);
  lo0 = deg>0 ? a[2]+mn[2] : 0.f; lo1 = deg>0 ? a[3]+mn[3] : 0.f;
  hi0 = deg>0 ? a[2]+mx[2] : 0.f; hi1 = deg>0 ? a[3]+mx[3] : 0.f;
  unsigned o1 = pk(mean0, mean1);
  unsigned l1 = pk(lo0, lo1), h1 = pk(hi0, hi1), t1 = pk(sd0, sd1);

  bf16* ag = agg + n*320 + fo;
  *(uint2*)(ag)       = make_uint2(o0, o1);
  *(uint2*)(ag + 80)  = make_uint2(l0, l1);
  *(uint2*)(ag + 160) = make_uint2(h0, h1);
  *(uint2*)(ag + 240) = make_uint2(t0, t1);
}

// ------------------------------------------------------------------ fused mean-pool + head
__global__ __launch_bounds__(128) void k_poolmlp(const float* __restrict__ h,
                        const int* __restrict__ batch,
                        const void* __restrict__ mlpW, const void* __restrict__ mlpb,
                        const int* __restrict__ flag, void* __restrict__ outp){
  __shared__ float sred[128];
  __shared__ int sb[2];
  int g = blockIdx.x;
  int t = threadIdx.x;
  if (t < 2){
    int target = g + t;
    int lo = 0, hi = NN;
    while (lo < hi){ int mid = (lo + hi) >> 1; if (batch[mid] < target) lo = mid + 1; else hi = mid; }
    sb[t] = lo;
  }
  __syncthreads();
  int lo = sb[0], hi = sb[1];
  float s = 0.f;
  if (t < 80)
    for (int n = lo; n < hi; n++) s += h[n*80 + t];
  int fl = flag[0];
  float wv = (t < 80) ? rdw(mlpW, t, fl) : 0.f;
  sred[t] = s * wv;
  __syncthreads();
  for (int off = 64; off > 0; off >>= 1){
    if (t < off) sred[t] += sred[t + off];
    __syncthreads();
  }
  if (t == 0){
    float cnt = (float)(hi - lo); if (cnt < 1.f) cnt = 1.f;
    float r = sred[0]/cnt + rdw(mlpb, 0, fl);
    if (fl) ((float*)outp)[g] = r;
    else    ((bf16*)outp)[g] = f2b(r);
  }
}

// ------------------------------------------------------------------ launch
extern "C" void kernel_launch(void* const* d_in, const int* in_sizes, int n_in,
                              void* d_out, int out_size, void* d_ws, size_t ws_size,
                              hipStream_t stream)
{
  const int*  x     = (const int*) d_in[0];
  const int*  ei    = (const int*) d_in[1];
  const int*  batch = (const int*) d_in[2];
  const void* avgp  = d_in[3];
  const void* aemb  = d_in[4];
  const void* preW  = d_in[5];
  const void* preb  = d_in[6];
  const void* postW = d_in[7];
  const void* postb = d_in[8];
  const void* linW  = d_in[9];
  const void* linb  = d_in[10];
  const void* bng   = d_in[11];
  const void* bnb   = d_in[12];
  const void* bnm   = d_in[13];
  const void* bnv   = d_in[14];
  const void* mlpW  = d_in[15];
  const void* mlpb  = d_in[16];

  char* w = (char*)d_ws;
  int*   flag   = (int*)  (w + 400000);       //       256  (zeroed)
  int*   rowptr = (int*)  (w + 401280);       //   200,064
  int*   colidx = (int*)  (w + 601344);       // 3,200,000
  float* scf    = (float*)(w + 3801344);      //   200,000
  float* invf   = (float*)(w + 4001344);      //   200,000
  float* bias1  = (float*)(w + 4201344);      //     2,560
  float* bias2  = (float*)(w + 4203904);      //     1,280
  bf16*  Btl    = (bf16*) (w + 4205184);      //    61,440
  bf16*  Bt1    = (bf16*) (w + 4266624);      //   122,880
  bf16*  Bt2    = (bf16*) (w + 4389504);      //   798,720
  float* h      = (float*)(w + 5188224);      // 16,000,000  f32 [N,80]
  bf16*  Ua     = (bf16*) (w + 21188224);     //  8,000,000  bf16 [N,80]
  bf16*  Ub     = (bf16*) (w + 29188224);     //  8,000,000  bf16 [N,80]
  bf16*  agg    = (bf16*) (w + 45188224);     // 32,000,000  bf16 [N,320]
  // pre-loop overlays inside the agg region:
  bf16*  pwb    = (bf16*) (w + 45188224);     //   665,600
  float* Wf     = (float*)(w + 45853824);     // 1,331,200
  int* staging  = (int*)  (w + 47185024);     // 3,200,000
  int* chunkcnt = (int*)  (w + 50385024);     //   613,088  [NCH][NBUCK]
  int* btotal   = (int*)  (w + 52831120);     //     3,128
  int* bbase    = (int*)  (w + 52834248);     //     3,136  (NBUCK+1)
  // total 77,188,224 B

  k_zero <<<1, 256, 0, stream>>>(flag, 64);
  k_probe<<<16, 256, 0, stream>>>(aemb, flag);

  // atomic-free CSR build
  k_hist <<<NCH, 256, 0, stream>>>(ei, chunkcnt);
  k_cscan<<<NBUCK, 256, 0, stream>>>(chunkcnt, btotal);
  k_bscan<<<1, 256, 0, stream>>>(btotal, bbase);
  k_place<<<NCH, 256, 0, stream>>>(ei, chunkcnt, bbase, staging);

  k_prep_all<<<1662, 256, 0, stream>>>(preW, preb, postW, postb, linW, linb,
                                       bng, bnb, bnm, bnv, flag,
                                       pwb, Btl, Bt1, bias1, bias2);

  // Wf[i] = postW[i](bf16) @ Btl[i]^T   (f32 out)
  k_mgemm<0,1,96,100><<<dim3(17,1,4), 256, 0, stream>>>(
      pwb, 80, 80, nullptr, 0, 0,
      Btl, 96, 80, nullptr, Wf, nullptr, 80, 1040,
      166400, 15360, 332800);
  k_prep_Bt2<<<(4*240*416 + 255)/256, 256, 0, stream>>>(Wf, Bt2);

  k_atom <<<(NN*10 + 255)/256, 256, 0, stream>>>(x, aemb, flag, h);

  // fused rowptr/scf/invf + counting-sorted colidx
  k_csr<<<NBUCK, 256, 0, stream>>>(staging, bbase, avgp, flag, rowptr, scf, invf, colidx);

  // layer-0 GEMM1 (subsequent layers' GEMM1 are fused into k_g2's tail)
  k_mgemm<1,2,96,100><<<dim3((NN + 63)/64,1,1), 256, 0, stream>>>(
      h, 80, 80, nullptr, 0, 0,
      Bt1, 96, 160, bias1, Ua, Ub, 0, NN,
      0, 0, 0);
  const int gx2 = (NN + 31)/32;   // 1563
  for (int i = 0; i < 4; i++){
    k_agg<<<(NN + 11)/12, 256, 0, stream>>>(Ua, Ub, rowptr, colidx, agg);
    const bf16* nBt1   = (i < 3) ? (Bt1 + (i+1)*15360) : nullptr;
    const float* nb1   = (i < 3) ? (bias1 + (i+1)*160) : bias1;
    k_g2<<<dim3(gx2,1,1), 256, 0, stream>>>(
        h, agg, Bt2 + i*99840, bias2 + i*80, scf, invf, h,
        nBt1, nb1, Ua, Ub);
  }

  k_poolmlp<<<NGR, 128, 0, stream>>>(h, batch, mlpW, mlpb, flag, d_out);
}

// Round 12
// 524.530 us; speedup vs baseline: 1.3849x; 1.0941x over previous
//
#include <hip/hip_runtime.h>
#include <hip/hip_bf16.h>

#define NN 50000
#define NE 800000
#define FD 80
#define NGR 1024
#define NF 9

// bucketed CSR sort (atomic-free counting sort)
#define BSH 6
#define NBUCK ((NN + 63) >> 6)     // 782 node-buckets of 64
#define CSH 12
#define NCH ((NE + 4095) >> 12)    // 196 edge-chunks of 4096
#define BCAP 2048

using bf16 = __hip_bfloat16;
typedef __attribute__((ext_vector_type(8))) short bf16x8;
typedef __attribute__((ext_vector_type(4))) float f32x4;

static __device__ __forceinline__ float b2f(bf16 v){ return __bfloat162float(v); }
static __device__ __forceinline__ bf16 f2b(float v){ return __float2bfloat16(v); }
static __device__ __forceinline__ float rdw(const void* p, int i, int fl){
  return fl ? ((const float*)p)[i] : b2f(((const bf16*)p)[i]);
}
static __device__ __forceinline__ unsigned pk(float a, float b){
  bf16 x = f2b(a), y = f2b(b);
  return (unsigned)*(unsigned short*)&x | ((unsigned)*(unsigned short*)&y << 16);
}
// 8B-granule LDS access (strides are 8B- but not 16B-aligned)
static __device__ __forceinline__ bf16x8 ldsld8(const short* p){
  union { bf16x8 v; uint2 u[2]; } r;
  r.u[0] = *(const uint2*)(p);
  r.u[1] = *(const uint2*)(p + 4);
  return r.v;
}
static __device__ __forceinline__ void ldsst16(short* p, uint4 v){
  *(uint2*)(p)     = make_uint2(v.x, v.y);
  *(uint2*)(p + 4) = make_uint2(v.z, v.w);
}

// ------------------------------------------------------------------ utility
__global__ void k_zero(int* __restrict__ p, int n){
  int t = blockIdx.x*256 + threadIdx.x;
  if (t < n) p[t] = 0;
}

__global__ void k_probe(const void* __restrict__ emb, int* __restrict__ flag){
  int t = blockIdx.x*256 + threadIdx.x;
  float v = b2f(((const bf16*)emb)[t]);
  if (!(fabsf(v) < 1e4f)) atomicOr(flag, 1);
}

// ------------------------------------------------------------------ fused weight prep
// Bt1 is emitted in K-step-major FRAGMENT-TILED layout: element (c,k) at
// ks*160*32 + c*32 + q*8 + kk  (k = ks*32+q*8+kk) -> one wave's MFMA B-frag
// load is a contiguous 1KB segment (direct-global, no LDS staging).
__global__ __launch_bounds__(256) void k_prep_all(
    const void* __restrict__ preW, const void* __restrict__ preb,
    const void* __restrict__ postW, const void* __restrict__ postb,
    const void* __restrict__ linW, const void* __restrict__ linb,
    const void* __restrict__ bng, const void* __restrict__ bnb,
    const void* __restrict__ bnm, const void* __restrict__ bnv,
    const int* __restrict__ flag,
    bf16* __restrict__ pwb, bf16* __restrict__ Btl, bf16* __restrict__ Bt1,
    float* __restrict__ bias1, float* __restrict__ bias2)
{
  int fl = flag[0];
  int b = blockIdx.x;
  if (b < 1300){
    int t = b*256 + threadIdx.x;
    pwb[t] = f2b(rdw(postW, t, fl));
  } else if (b < 1420){
    int t = (b - 1300)*256 + threadIdx.x;
    int j = t % 96, c = (t/96) % 80, i = t/(96*80);
    float v = 0.f;
    if (j < 80){
      float gs = rdw(bng, i*80 + c, fl) * rsqrtf(rdw(bnv, i*80 + c, fl) + 1e-5f);
      v = rdw(linW, i*6400 + j*80 + c, fl) * gs;
    }
    Btl[t] = f2b(v);
  } else if (b < 1660){
    int t = (b - 1420)*256 + threadIdx.x;
    int k = t % 96, c = (t/96) % 160, i = t/(96*160);
    float v = 0.f;
    if (k < 80)
      v = (c < 80) ? rdw(preW, (i*160 + k)*80 + c, fl)
                   : rdw(preW, (i*160 + 80 + k)*80 + (c - 80), fl);
    int of = ((k >> 5)*160 + c)*32 + (k & 31 & ~7) + (k & 7);  // ks*5120 + c*32 + q*8 + kk
    Bt1[i*15360 + of] = f2b(v);
    if (k == 0) bias1[i*160 + c] = (c < 80) ? rdw(preb, i*80 + c, fl) : 0.f;
  } else {
    int t = (b - 1660)*256 + threadIdx.x;
    if (t >= 4*80) return;
    int i = t / 80, f = t - i*80;
    float s = 0.f;
    for (int j = 0; j < 80; j++)
      s += rdw(postb, i*80 + j, fl) * rdw(linW, (i*80 + j)*80 + f, fl);
    s += rdw(linb, t, fl);
    float gs = rdw(bng, t, fl) * rsqrtf(rdw(bnv, t, fl) + 1e-5f);
    bias2[t] = (s - rdw(bnm, t, fl)) * gs + rdw(bnb, t, fl);
  }
}

// Bt2 in fragment-tiled layout: element (c,k) at ks*240*32 + c*32 + (k&31).
__global__ void k_prep_Bt2(const float* __restrict__ Wf, bf16* __restrict__ Bt2){
  int t = blockIdx.x*256 + threadIdx.x;
  if (t >= 4*240*416) return;
  int k = t % 416;
  int c = (t/416) % 240;
  int i = t/(416*240);
  float v = 0.f;
  if (k < 400){
    int blk = c/80, f = c - blk*80;
    if (blk == 0) v = Wf[(i*1040 + k)*80 + f];
    else if (k >= 80){
      int row = (blk == 1 ? 400 : 720) + (k - 80);
      v = Wf[(i*1040 + row)*80 + f];
    }
  }
  int of = (k >> 5)*7680 + c*32 + (k & 31);
  Bt2[i*99840 + of] = f2b(v);
}

// ------------------------------------------------------------------ graph prep
// Vectorized: one thread per (node, 8-feature block); 9 x 16B gathers + float4
// stores. Summation order (c ascending) identical to the scalar version.
__global__ void k_atom(const int* __restrict__ x, const void* __restrict__ emb,
                       const int* __restrict__ flag, float* __restrict__ h){
  int fl = flag[0];
  int gid = blockIdx.x*256 + threadIdx.x;
  if (gid >= NN*10) return;
  int n = gid / 10, fb = gid - n*10;
  int f0 = fb*8;
  int xr[NF];
  #pragma unroll
  for (int c = 0; c < NF; c++) xr[c] = x[n*NF + c];
  float s[8] = {0.f,0.f,0.f,0.f,0.f,0.f,0.f,0.f};
  if (fl){
    #pragma unroll
    for (int c = 0; c < NF; c++){
      const float* ep = (const float*)emb + (c*119 + xr[c])*80 + f0;
      float4 a = *(const float4*)ep, b = *(const float4*)(ep + 4);
      s[0]+=a.x; s[1]+=a.y; s[2]+=a.z; s[3]+=a.w;
      s[4]+=b.x; s[5]+=b.y; s[6]+=b.z; s[7]+=b.w;
    }
  } else {
    #pragma unroll
    for (int c = 0; c < NF; c++){
      const bf16* ep = (const bf16*)emb + (c*119 + xr[c])*80 + f0;
      uint4 u = *(const uint4*)ep;
      s[0]+=__uint_as_float(u.x<<16); s[1]+=__uint_as_float(u.x&0xffff0000u);
      s[2]+=__uint_as_float(u.y<<16); s[3]+=__uint_as_float(u.y&0xffff0000u);
      s[4]+=__uint_as_float(u.z<<16); s[5]+=__uint_as_float(u.z&0xffff0000u);
      s[6]+=__uint_as_float(u.w<<16); s[7]+=__uint_as_float(u.w&0xffff0000u);
    }
  }
  float* hp = h + n*80 + f0;
  *(float4*)hp       = make_float4(s[0],s[1],s[2],s[3]);
  *(float4*)(hp + 4) = make_float4(s[4],s[5],s[6],s[7]);
}

// ---- atomic-free CSR build: hist -> cscan -> bscan -> place -> csr ----

// Per-chunk bucket histogram (coalesced matrix write). 4096 edges/chunk.
__global__ __launch_bounds__(256) void k_hist(const int* __restrict__ ei,
                                              int* __restrict__ chunkcnt){
  __shared__ int hist[NBUCK];
  int c = blockIdx.x, t = threadIdx.x;
  for (int i = t; i < NBUCK; i += 256) hist[i] = 0;
  __syncthreads();
  #pragma unroll
  for (int j = 0; j < 16; j++){
    int e = (c << CSH) + j*256 + t;
    if (e < NE) atomicAdd(&hist[ei[NE + e] >> BSH], 1);
  }
  __syncthreads();
  for (int i = t; i < NBUCK; i += 256) chunkcnt[c*NBUCK + i] = hist[i];
}

// Per-bucket exclusive scan over chunks (in-place) + bucket totals.
__global__ __launch_bounds__(256) void k_cscan(int* __restrict__ chunkcnt,
                                               int* __restrict__ btotal){
  __shared__ int buf[256];
  int b = blockIdx.x, t = threadIdx.x;
  int v[4]; int s = 0;
  #pragma unroll
  for (int j = 0; j < 4; j++){
    int c = t*4 + j;
    v[j] = (c < NCH) ? chunkcnt[c*NBUCK + b] : 0;
    s += v[j];
  }
  buf[t] = s;
  __syncthreads();
  for (int off = 1; off < 256; off <<= 1){
    int xv = (t >= off) ? buf[t - off] : 0;
    __syncthreads();
    buf[t] += xv;
    __syncthreads();
  }
  int excl = buf[t] - s;
  #pragma unroll
  for (int j = 0; j < 4; j++){
    int c = t*4 + j;
    if (c < NCH){ chunkcnt[c*NBUCK + b] = excl; excl += v[j]; }
  }
  if (t == 255) btotal[b] = buf[255];
}

// Exclusive scan of bucket totals -> bucket base offsets (bbase[NBUCK] = NE).
__global__ __launch_bounds__(256) void k_bscan(const int* __restrict__ btotal,
                                               int* __restrict__ bbase){
  __shared__ int buf[256];
  int t = threadIdx.x;
  int v[4]; int s = 0;
  #pragma unroll
  for (int j = 0; j < 4; j++){
    int c = t*4 + j;
    v[j] = (c < NBUCK) ? btotal[c] : 0;
    s += v[j];
  }
  buf[t] = s;
  __syncthreads();
  for (int off = 1; off < 256; off <<= 1){
    int xv = (t >= off) ? buf[t - off] : 0;
    __syncthreads();
    buf[t] += xv;
    __syncthreads();
  }
  int excl = buf[t] - s;
  #pragma unroll
  for (int j = 0; j < 4; j++){
    int c = t*4 + j;
    if (c < NBUCK){ bbase[c] = excl; excl += v[j]; }
  }
  if (t == 255) bbase[NBUCK] = buf[255];
}

// Place each edge into its bucket's staging range; rank via LDS atomics.
__global__ __launch_bounds__(256) void k_place(const int* __restrict__ ei,
                        const int* __restrict__ chunkcnt, const int* __restrict__ bbase,
                        int* __restrict__ staging){
  __shared__ int basep[NBUCK];
  __shared__ int cur[NBUCK];
  int c = blockIdx.x, t = threadIdx.x;
  for (int i = t; i < NBUCK; i += 256){
    basep[i] = chunkcnt[c*NBUCK + i] + bbase[i];
    cur[i] = 0;
  }
  __syncthreads();
  #pragma unroll
  for (int j = 0; j < 16; j++){
    int e = (c << CSH) + j*256 + t;
    if (e < NE){
      int d = ei[NE + e], s = ei[e];
      int b = d >> BSH;
      int r = atomicAdd(&cur[b], 1);
      staging[basep[b] + r] = (s << BSH) | (d & 63);
    }
  }
}

// Fused per-bucket finalize: node counts -> rowptr/scf/invf + counting sort
// into colidx (sequential reads, coalesced writes).
__global__ __launch_bounds__(256) void k_csr(const int* __restrict__ staging,
                        const int* __restrict__ bbase, const void* __restrict__ avgp,
                        const int* __restrict__ flag, int* __restrict__ rowptr,
                        float* __restrict__ scf, float* __restrict__ invf,
                        int* __restrict__ colidx){
  __shared__ int lcnt[64], lrp[64], lcur[64];
  __shared__ int colbuf[BCAP];
  int b = blockIdx.x, t = threadIdx.x;
  int base = bbase[b];
  int cnt  = bbase[b+1] - base;
  if (t < 64){ lcnt[t] = 0; lcur[t] = 0; }
  __syncthreads();
  for (int i = t; i < cnt; i += 256)
    atomicAdd(&lcnt[staging[base + i] & 63], 1);
  __syncthreads();
  if (t < 64) lrp[t] = lcnt[t];
  __syncthreads();
  for (int off = 1; off < 64; off <<= 1){
    int xv = (t < 64 && t >= off) ? lrp[t - off] : 0;
    __syncthreads();
    if (t < 64) lrp[t] += xv;
    __syncthreads();
  }
  int n0 = b << BSH;
  if (t < 64){
    int ex = lrp[t] - lcnt[t];
    lrp[t] = ex;
    int n = n0 + t;
    if (n < NN){
      rowptr[n] = base + ex;
      float degc = (float)(lcnt[t] > 0 ? lcnt[t] : 1);
      float logd = logf(degc + 1.f);
      float avg = rdw(avgp, 0, flag[0]);
      scf[n] = logd / avg;
      invf[n] = avg / logd;
    }
  }
  if (b == 0 && t == 0) rowptr[NN] = NE;
  __syncthreads();
  if (cnt <= BCAP){
    for (int i = t; i < cnt; i += 256){
      int v = staging[base + i];
      int l = v & 63;
      int pos = lrp[l] + atomicAdd(&lcur[l], 1);
      colbuf[pos] = v >> BSH;
    }
    __syncthreads();
    for (int i = t; i < cnt; i += 256)
      colidx[base + i] = colbuf[i];
  } else {
    for (int i = t; i < cnt; i += 256){
      int v = staging[base + i];
      int l = v & 63;
      int pos = lrp[l] + atomicAdd(&lcur[l], 1);
      colidx[base + pos] = v >> BSH;
    }
  }
}

// ------------------------------------------------------------------ MFMA GEMM (r4 structure; Wf only)
template<int AF32, int OUTMODE, int K_, int AST>
__global__ __launch_bounds__(256) void k_mgemm(
    const void* __restrict__ A1p, int s1, int KA,
    const bf16* __restrict__ A2, int s2, int KB,
    const bf16* __restrict__ Btp, int Bts, int Ncols,
    const float* __restrict__ bias,
    void* __restrict__ Cbase, void* __restrict__ Cp2, int Cstride, int M,
    int lA1b, int lBtb, int lCb)
{
  const void* A1 = (const char*)A1p + (size_t)blockIdx.z*lA1b;
  const bf16* Bt = (const bf16*)((const char*)Btp + (size_t)blockIdx.z*lBtb);
  void* Cp = (char*)Cbase + (size_t)blockIdx.z*lCb;

  constexpr int NKT = K_ / 32;
  __shared__ short As[64*AST];
  __shared__ short Bs[256*44];

  const int tid = threadIdx.x;
  const int row0 = blockIdx.x * 64;
  const int wave = tid >> 6, lane = tid & 63;
  const int wc = wave * 64;
  const int m16 = lane & 15, q = lane >> 4;

  const int ra = tid >> 2, ka = (tid & 3) * 8;
  const int cb = tid >> 2, kb = (tid & 3) * 8;

  f32x4 acc[4][4] = {};
  uint4 pb[4];

#define LOADB(k0_) { int kgb = (k0_) + kb;                                     \
    _Pragma("unroll")                                                          \
    for (int j = 0; j < 4; j++){                                               \
      int col = cb + j*64;                                                     \
      pb[j].x = pb[j].y = pb[j].z = pb[j].w = 0u;                              \
      if (col < Ncols) pb[j] = *(const uint4*)(Bt + col*Bts + kgb);            \
    } }

  LOADB(0);

  {
    const int grow = row0 + ra;
    uint4 tA[NKT];
    #pragma unroll
    for (int c = 0; c < NKT; c++){
      int kg = c*32 + ka;
      uint4 pa; pa.x = pa.y = pa.z = pa.w = 0u;
      if (grow < M){
        if (kg < KA){
          if (AF32){
            const float* ap = (const float*)A1 + grow*s1 + kg;
            float4 f0 = *(const float4*)ap;
            float4 f1 = *(const float4*)(ap + 4);
            pa.x = pk(f0.x, f0.y); pa.y = pk(f0.z, f0.w);
            pa.z = pk(f1.x, f1.y); pa.w = pk(f1.z, f1.w);
          } else {
            pa = *(const uint4*)((const bf16*)A1 + grow*s1 + kg);
          }
        } else if (kg - KA < KB){
          pa = *(const uint4*)(A2 + grow*s2 + (kg - KA));
        }
      }
      tA[c] = pa;
    }
    #pragma unroll
    for (int c = 0; c < NKT; c++)
      ldsst16(&As[ra*AST + c*32 + ka], tA[c]);
  }
  __syncthreads();

  #pragma unroll
  for (int ks = 0; ks < NKT; ks++){
    #pragma unroll
    for (int j = 0; j < 4; j++)
      ldsst16(&Bs[(cb + j*64)*44 + kb], pb[j]);
    __syncthreads();

    if (ks + 1 < NKT) LOADB((ks + 1)*32);

    bf16x8 af[4], bfv[4];
    #pragma unroll
    for (int rt = 0; rt < 4; rt++)
      af[rt] = ldsld8(&As[(rt*16 + m16)*AST + ks*32 + q*8]);
    #pragma unroll
    for (int ct = 0; ct < 4; ct++)
      bfv[ct] = ldsld8(&Bs[(wc + ct*16 + m16)*44 + q*8]);
    #pragma unroll
    for (int rt = 0; rt < 4; rt++)
      #pragma unroll
      for (int ct = 0; ct < 4; ct++)
        acc[rt][ct] = __builtin_amdgcn_mfma_f32_16x16x32_bf16(af[rt], bfv[ct], acc[rt][ct], 0, 0, 0);
    __syncthreads();
  }
#undef LOADB

  #pragma unroll
  for (int rt = 0; rt < 4; rt++){
    #pragma unroll
    for (int rr = 0; rr < 4; rr++){
      int row = row0 + rt*16 + q*4 + rr;
      if (row >= M) continue;
      #pragma unroll
      for (int ct = 0; ct < 4; ct++){
        int col = wc + ct*16 + m16;
        if (col >= Ncols) continue;
        float v = acc[rt][ct][rr] + (bias ? bias[col] : 0.f);
        if (OUTMODE == 1) ((float*)Cp)[row*Cstride + col] = v;
        else {
          if (col < 80) ((bf16*)Cp )[row*80 + col]      = f2b(v);
          else          ((bf16*)Cp2)[row*80 + col - 80] = f2b(v);
        }
      }
    }
  }
}

// ------------------------------------------------------------------ layer-0 GEMM1 (direct tiled-B, barrier-free)
__global__ __launch_bounds__(256) void k_g1(
    const float* __restrict__ h, const bf16* __restrict__ Bt1t,
    const float* __restrict__ bias1v,
    bf16* __restrict__ Ua, bf16* __restrict__ Ub)
{
  __shared__ short hA[32*100];   // 6,400 B
  const int tid = threadIdx.x;
  const int row0 = blockIdx.x * 32;
  const int wave = tid >> 6, lane = tid & 63;
  const int wc = wave * 64;
  const int m16 = lane & 15, q = lane >> 4;
  const int ra = tid >> 3, ka0 = (tid & 7) * 8;

  // stage h rows (f32->bf16); zero pad k in [80,96)
  {
    int grow = row0 + ra;
    #pragma unroll
    for (int c = 0; c < 2; c++){
      int kg = ka0 + c*64;
      if (kg < 96){
        uint4 pa; pa.x = pa.y = pa.z = pa.w = 0u;
        if (kg < 80 && grow < NN){
          const float* ap = h + grow*80 + kg;
          float4 f0 = *(const float4*)ap, f1 = *(const float4*)(ap + 4);
          pa.x = pk(f0.x, f0.y); pa.y = pk(f0.z, f0.w);
          pa.z = pk(f1.x, f1.y); pa.w = pk(f1.z, f1.w);
        }
        ldsst16(&hA[ra*100 + kg], pa);
      }
    }
  }
  __syncthreads();

  const bf16* bp1[4];
  #pragma unroll
  for (int ct = 0; ct < 4; ct++){
    int col = wc + ct*16 + m16;
    if (col >= 160) col = 0;
    bp1[ct] = Bt1t + col*32 + q*8;
  }
  f32x4 acc[2][4] = {};
  #pragma unroll
  for (int ks = 0; ks < 3; ks++){
    bf16x8 bfv[4], af[2];
    #pragma unroll
    for (int ct = 0; ct < 4; ct++)
      bfv[ct] = *(const bf16x8*)(bp1[ct] + ks*5120);
    #pragma unroll
    for (int rt = 0; rt < 2; rt++)
      af[rt] = ldsld8(&hA[(rt*16 + m16)*100 + ks*32 + q*8]);
    #pragma unroll
    for (int rt = 0; rt < 2; rt++)
      #pragma unroll
      for (int ct = 0; ct < 4; ct++)
        acc[rt][ct] = __builtin_amdgcn_mfma_f32_16x16x32_bf16(af[rt], bfv[ct], acc[rt][ct], 0, 0, 0);
  }
  #pragma unroll
  for (int rt = 0; rt < 2; rt++){
    #pragma unroll
    for (int rr = 0; rr < 4; rr++){
      int row = row0 + rt*16 + q*4 + rr;
      if (row >= NN) continue;
      #pragma unroll
      for (int ct = 0; ct < 4; ct++){
        int col = wc + ct*16 + m16;
        if (col >= 160) continue;
        float v = acc[rt][ct][rr] + bias1v[col];
        if (col < 80) Ua[row*80 + col]      = f2b(v);
        else          Ub[row*80 + col - 80] = f2b(v);
      }
    }
  }
}

// ------------------------------------------------------------------ GEMM2 + fused next-layer GEMM1
// 32-row tile, DIRECT TILED-B (no Bs LDS, no K-loop barriers; round-11
// evidence: 2-barrier-per-K-step structure is the floor; round-5's direct-B
// failure was layout-induced coalescing, fixed by the fragment-tiled Bt2).
// LDS = As only (26,880 B) -> 5 blocks/CU.
__global__ __launch_bounds__(256) void k_g2(
    const float* __restrict__ h, const bf16* __restrict__ agg,
    const bf16* __restrict__ Bt, const float* __restrict__ bias2v,
    const float* __restrict__ scf, const float* __restrict__ invf,
    float* __restrict__ hp,
    const bf16* __restrict__ Bt1n, const float* __restrict__ bias1n,
    bf16* __restrict__ Ua, bf16* __restrict__ Ub)
{
  constexpr int AST = 420, NKT = 13;
  __shared__ short As[32*AST];   // 26,880 B
  bf16* eL = (bf16*)As;                 // epilogue staging 32x248 (15,872 B)
  bf16* hA = (bf16*)(As + 8192);        // h_new panel 32x100 (bytes 16,384..22,784)

  const int tid = threadIdx.x;
  const int row0 = blockIdx.x * 32;
  const int wave = tid >> 6, lane = tid & 63;
  const int wc = wave * 64;
  const int m16 = lane & 15, q = lane >> 4;
  const int ra = tid >> 3;           // 32 rows, 8 threads/row
  const int ka0 = (tid & 7) * 8;     // chunk start; stride 64 shorts

  // ---- stage A panel: k<80 from h (f32->bf16), 80<=k<400 from agg, else 0
  {
    const int grow = row0 + ra;
    uint4 tA[7];
    #pragma unroll
    for (int c = 0; c < 7; c++){
      int kg = ka0 + c*64;
      uint4 pa; pa.x = pa.y = pa.z = pa.w = 0u;
      if (kg < 416 && grow < NN){
        if (kg < 80){
          const float* ap = h + grow*80 + kg;
          float4 f0 = *(const float4*)ap;
          float4 f1 = *(const float4*)(ap + 4);
          pa.x = pk(f0.x, f0.y); pa.y = pk(f0.z, f0.w);
          pa.z = pk(f1.x, f1.y); pa.w = pk(f1.z, f1.w);
        } else if (kg < 400){
          pa = *(const uint4*)(agg + grow*320 + (kg - 80));
        }
      }
      tA[c] = pa;
    }
    #pragma unroll
    for (int c = 0; c < 7; c++){
      int kg = ka0 + c*64;
      if (kg < 416) ldsst16(&As[ra*AST + kg], tA[c]);
    }
  }

  // ---- per-lane tiled-B base pointers (OOB cols clamped; their acc unused)
  const bf16* bp[4];
  #pragma unroll
  for (int ct = 0; ct < 4; ct++){
    int col = wc + ct*16 + m16;
    if (col >= 240) col = 0;
    bp[ct] = Bt + col*32 + q*8;
  }
  __syncthreads();   // A panel ready

  f32x4 acc[2][4] = {};

  // ---- barrier-free K loop: direct-global B frags (contiguous 1KB/wave/frag)
  #pragma unroll
  for (int ks = 0; ks < NKT; ks++){
    bf16x8 bfv[4], af[2];
    #pragma unroll
    for (int ct = 0; ct < 4; ct++)
      bfv[ct] = *(const bf16x8*)(bp[ct] + ks*7680);
    #pragma unroll
    for (int rt = 0; rt < 2; rt++)
      af[rt] = ldsld8(&As[(rt*16 + m16)*AST + ks*32 + q*8]);
    #pragma unroll
    for (int rt = 0; rt < 2; rt++)
      #pragma unroll
      for (int ct = 0; ct < 4; ct++)
        acc[rt][ct] = __builtin_amdgcn_mfma_f32_16x16x32_bf16(af[rt], bfv[ct], acc[rt][ct], 0, 0, 0);
  }
  __syncthreads();   // all waves done reading As before eL overwrite

  // ---- epilogue: stage P|Q|R in eL
  #pragma unroll
  for (int rt = 0; rt < 2; rt++){
    #pragma unroll
    for (int ct = 0; ct < 4; ct++){
      int col = wc + ct*16 + m16;
      if (col >= 240) continue;
      #pragma unroll
      for (int rr = 0; rr < 4; rr++){
        int r = rt*16 + q*4 + rr;
        eL[r*248 + col] = f2b(acc[rt][ct][rr]);
      }
    }
  }
  __syncthreads();

  // ---- combine -> h_new; write global f32 + LDS bf16 panel
  #pragma unroll
  for (int i = 0; i < 10; i++){
    int idx = tid + i*256;
    int r = idx / 80, c = idx - r*80;
    int row = row0 + r;
    if (row < NN){
      float P = b2f(eL[r*248 + c]);
      float Q = b2f(eL[r*248 + 80 + c]);
      float R = b2f(eL[r*248 + 160 + c]);
      float o = P + scf[row]*Q + invf[row]*R + bias2v[c];
      float hn = hp[row*80 + c] + fmaxf(o, 0.f);
      hp[row*80 + c] = hn;
      if (Bt1n) hA[r*100 + c] = f2b(hn);
    } else if (Bt1n && idx < 32*80){
      hA[r*100 + c] = f2b(0.f);   // tail rows: defined values for mini-GEMM
    }
  }
  if (Bt1n && tid < 128){
    // zero pad k in [80,96)
    int r = tid >> 2, off = 80 + (tid & 3)*4;
    *(uint2*)&hA[r*100 + off] = make_uint2(0u, 0u);
  }
  __syncthreads();

  // ---- mini-GEMM: U = h_new @ Bt1[next] (tiled-B, barrier-free)
  if (Bt1n){
    const bf16* bp1[4];
    #pragma unroll
    for (int ct = 0; ct < 4; ct++){
      int col = wc + ct*16 + m16;
      if (col >= 160) col = 0;
      bp1[ct] = Bt1n + col*32 + q*8;
    }
    f32x4 acc2[2][4] = {};
    #pragma unroll
    for (int ks = 0; ks < 3; ks++){
      bf16x8 bfv[4], af[2];
      #pragma unroll
      for (int ct = 0; ct < 4; ct++)
        bfv[ct] = *(const bf16x8*)(bp1[ct] + ks*5120);
      #pragma unroll
      for (int rt = 0; rt < 2; rt++)
        af[rt] = ldsld8((const short*)hA + (rt*16 + m16)*100 + ks*32 + q*8);
      #pragma unroll
      for (int rt = 0; rt < 2; rt++)
        #pragma unroll
        for (int ct = 0; ct < 4; ct++)
          acc2[rt][ct] = __builtin_amdgcn_mfma_f32_16x16x32_bf16(af[rt], bfv[ct], acc2[rt][ct], 0, 0, 0);
    }
    #pragma unroll
    for (int rt = 0; rt < 2; rt++){
      #pragma unroll
      for (int rr = 0; rr < 4; rr++){
        int row = row0 + rt*16 + q*4 + rr;
        if (row >= NN) continue;
        #pragma unroll
        for (int ct = 0; ct < 4; ct++){
          int col = wc + ct*16 + m16;
          if (col >= 160) continue;
          float v = acc2[rt][ct][rr] + bias1n[col];
          if (col < 80) Ua[row*80 + col]      = f2b(v);
          else          Ub[row*80 + col - 80] = f2b(v);
        }
      }
    }
  }
}

// ------------------------------------------------------------------ aggregation
// 3 nodes/wave: lane/20 = node slot, (lane%20)*4 = feature offset (uint2 = 4 bf16)
__global__ __launch_bounds__(256) void k_agg(const bf16* __restrict__ Ua,
                      const bf16* __restrict__ Ub,
                      const int* __restrict__ rowptr,
                      const int* __restrict__ colidx, bf16* __restrict__ agg)
{
  int lane = threadIdx.x & 63;
  int slot = lane / 20;
  int n = blockIdx.x*12 + (threadIdx.x >> 6)*3 + slot;
  if (slot >= 3 || n >= NN) return;
  int fo = (lane - slot*20) * 4;
  int rs = rowptr[n], re = rowptr[n+1];
  int deg = re - rs;

  float a[4];
  {
    uint2 ua = *(const uint2*)(Ua + n*80 + fo);
    a[0] = __uint_as_float(ua.x << 16);
    a[1] = __uint_as_float(ua.x & 0xffff0000u);
    a[2] = __uint_as_float(ua.y << 16);
    a[3] = __uint_as_float(ua.y & 0xffff0000u);
  }
  float sb[4] = {0.f,0.f,0.f,0.f}, sq[4] = {0.f,0.f,0.f,0.f};
  float mn[4] = {1e30f,1e30f,1e30f,1e30f}, mx[4] = {-1e30f,-1e30f,-1e30f,-1e30f};

#define ACC2(w, o) { \
    float b0 = __uint_as_float((w) << 16); \
    float b1 = __uint_as_float((w) & 0xffff0000u); \
    sb[o] += b0; sq[o] += b0*b0; mn[o] = fminf(mn[o],b0); mx[o] = fmaxf(mx[o],b0); \
    sb[o+1] += b1; sq[o+1] += b1*b1; mn[o+1] = fminf(mn[o+1],b1); mx[o+1] = fmaxf(mx[o+1],b1); }

  for (int e = rs; e < re; e += 8){
    int cnt = re - e; if (cnt > 8) cnt = 8;
    int s[8];
    #pragma unroll
    for (int j = 0; j < 8; j++) s[j] = (j < cnt) ? colidx[e + j] : s[0];
    uint2 u[8];
    #pragma unroll
    for (int j = 0; j < 8; j++) u[j] = *(const uint2*)(Ub + s[j]*80 + fo);
    #pragma unroll
    for (int j = 0; j < 8; j++){
      if (j < cnt){ ACC2(u[j].x, 0); ACC2(u[j].y, 2); }
    }
  }
#undef ACC2

  float degc = (float)(deg > 0 ? deg : 1);
  float inv = 1.f/degc;
  float dm = (float)deg;
  float mean0, mean1, v0, v1, sd0, sd1, lo0, lo1, hi0, hi1;

  mean0 = (dm*a[0] + sb[0])*inv; mean1 = (dm*a[1] + sb[1])*inv;
  v0 = (dm*a[0]*a[0] + 2.f*a[0]*sb[0] + sq[0])*inv - mean0*mean0;
  v1 = (dm*a[1]*a[1] + 2.f*a[1]*sb[1] + sq[1])*inv - mean1*mean1;
  sd0 = sqrtf(fmaxf(v0,0.f)+1e-5f); sd1 = sqrtf(fmaxf(v1,0.f)+1e-5f);
  lo0 = deg>0 ? a[0]+mn[0] : 0.f; lo1 = deg>0 ? a[1]+mn[1] : 0.f;
  hi0 = deg>0 ? a[0]+mx[0] : 0.f; hi1 = deg>0 ? a[1]+mx[1] : 0.f;
  unsigned o0 = pk(mean0, mean1);
  unsigned l0 = pk(lo0, lo1), h0 = pk(hi0, hi1), t0 = pk(sd0, sd1);

  mean0 = (dm*a[2] + sb[2])*inv; mean1 = (dm*a[3] + sb[3])*inv;
  v0 = (dm*a[2]*a[2] + 2.f*a[2]*sb[2] + sq[2])*inv - mean0*mean0;
  v1 = (dm*a[3]*a[3] + 2.f*a[3]*sb[3] + sq[3])*inv - mean1*mean1;
  sd0 = sqrtf(fmaxf(v0,0.f)+1e-5f); sd1 = sqrtf(fmaxf(v1,0.f)+1e-5f);
  lo0 = deg>0 ? a[2]+mn[2] : 0.f; lo1 = deg>0 ? a[2+1]+mn[3] : 0.f;
  hi0 = deg>0 ? a[2]+mx[2] : 0.f; hi1 = deg>0 ? a[3]+mx[3] : 0.f;
  unsigned o1 = pk(mean0, mean1);
  unsigned l1 = pk(lo0, lo1), h1 = pk(hi0, hi1), t1 = pk(sd0, sd1);

  bf16* ag = agg + n*320 + fo;
  *(uint2*)(ag)       = make_uint2(o0, o1);
  *(uint2*)(ag + 80)  = make_uint2(l0, l1);
  *(uint2*)(ag + 160) = make_uint2(h0, h1);
  *(uint2*)(ag + 240) = make_uint2(t0, t1);
}

// ------------------------------------------------------------------ fused mean-pool + head
__global__ __launch_bounds__(128) void k_poolmlp(const float* __restrict__ h,
                        const int* __restrict__ batch,
                        const void* __restrict__ mlpW, const void* __restrict__ mlpb,
                        const int* __restrict__ flag, void* __restrict__ outp){
  __shared__ float sred[128];
  __shared__ int sb[2];
  int g = blockIdx.x;
  int t = threadIdx.x;
  if (t < 2){
    int target = g + t;
    int lo = 0, hi = NN;
    while (lo < hi){ int mid = (lo + hi) >> 1; if (batch[mid] < target) lo = mid + 1; else hi = mid; }
    sb[t] = lo;
  }
  __syncthreads();
  int lo = sb[0], hi = sb[1];
  float s = 0.f;
  if (t < 80)
    for (int n = lo; n < hi; n++) s += h[n*80 + t];
  int fl = flag[0];
  float wv = (t < 80) ? rdw(mlpW, t, fl) : 0.f;
  sred[t] = s * wv;
  __syncthreads();
  for (int off = 64; off > 0; off >>= 1){
    if (t < off) sred[t] += sred[t + off];
    __syncthreads();
  }
  if (t == 0){
    float cnt = (float)(hi - lo); if (cnt < 1.f) cnt = 1.f;
    float r = sred[0]/cnt + rdw(mlpb, 0, fl);
    if (fl) ((float*)outp)[g] = r;
    else    ((bf16*)outp)[g] = f2b(r);
  }
}

// ------------------------------------------------------------------ launch
extern "C" void kernel_launch(void* const* d_in, const int* in_sizes, int n_in,
                              void* d_out, int out_size, void* d_ws, size_t ws_size,
                              hipStream_t stream)
{
  const int*  x     = (const int*) d_in[0];
  const int*  ei    = (const int*) d_in[1];
  const int*  batch = (const int*) d_in[2];
  const void* avgp  = d_in[3];
  const void* aemb  = d_in[4];
  const void* preW  = d_in[5];
  const void* preb  = d_in[6];
  const void* postW = d_in[7];
  const void* postb = d_in[8];
  const void* linW  = d_in[9];
  const void* linb  = d_in[10];
  const void* bng   = d_in[11];
  const void* bnb   = d_in[12];
  const void* bnm   = d_in[13];
  const void* bnv   = d_in[14];
  const void* mlpW  = d_in[15];
  const void* mlpb  = d_in[16];

  char* w = (char*)d_ws;
  int*   flag   = (int*)  (w + 400000);       //       256  (zeroed)
  int*   rowptr = (int*)  (w + 401280);       //   200,064
  int*   colidx = (int*)  (w + 601344);       // 3,200,000
  float* scf    = (float*)(w + 3801344);      //   200,000
  float* invf   = (float*)(w + 4001344);      //   200,000
  float* bias1  = (float*)(w + 4201344);      //     2,560
  float* bias2  = (float*)(w + 4203904);      //     1,280
  bf16*  Btl    = (bf16*) (w + 4205184);      //    61,440
  bf16*  Bt1    = (bf16*) (w + 4266624);      //   122,880  (tiled layout)
  bf16*  Bt2    = (bf16*) (w + 4389504);      //   798,720  (tiled layout)
  float* h      = (float*)(w + 5188224);      // 16,000,000  f32 [N,80]
  bf16*  Ua     = (bf16*) (w + 21188224);     //  8,000,000  bf16 [N,80]
  bf16*  Ub     = (bf16*) (w + 29188224);     //  8,000,000  bf16 [N,80]
  bf16*  agg    = (bf16*) (w + 45188224);     // 32,000,000  bf16 [N,320]
  // pre-loop overlays inside the agg region:
  bf16*  pwb    = (bf16*) (w + 45188224);     //   665,600
  float* Wf     = (float*)(w + 45853824);     // 1,331,200
  int* staging  = (int*)  (w + 47185024);     // 3,200,000
  int* chunkcnt = (int*)  (w + 50385024);     //   613,088  [NCH][NBUCK]
  int* btotal   = (int*)  (w + 52831120);     //     3,128
  int* bbase    = (int*)  (w + 52834248);     //     3,136  (NBUCK+1)
  // total 77,188,224 B

  k_zero <<<1, 256, 0, stream>>>(flag, 64);
  k_probe<<<16, 256, 0, stream>>>(aemb, flag);

  // atomic-free CSR build
  k_hist <<<NCH, 256, 0, stream>>>(ei, chunkcnt);
  k_cscan<<<NBUCK, 256, 0, stream>>>(chunkcnt, btotal);
  k_bscan<<<1, 256, 0, stream>>>(btotal, bbase);
  k_place<<<NCH, 256, 0, stream>>>(ei, chunkcnt, bbase, staging);

  k_prep_all<<<1662, 256, 0, stream>>>(preW, preb, postW, postb, linW, linb,
                                       bng, bnb, bnm, bnv, flag,
                                       pwb, Btl, Bt1, bias1, bias2);

  // Wf[i] = postW[i](bf16) @ Btl[i]^T   (f32 out)
  k_mgemm<0,1,96,100><<<dim3(17,1,4), 256, 0, stream>>>(
      pwb, 80, 80, nullptr, 0, 0,
      Btl, 96, 80, nullptr, Wf, nullptr, 80, 1040,
      166400, 15360, 332800);
  k_prep_Bt2<<<(4*240*416 + 255)/256, 256, 0, stream>>>(Wf, Bt2);

  k_atom <<<(NN*10 + 255)/256, 256, 0, stream>>>(x, aemb, flag, h);

  // fused rowptr/scf/invf + counting-sorted colidx
  k_csr<<<NBUCK, 256, 0, stream>>>(staging, bbase, avgp, flag, rowptr, scf, invf, colidx);

  const int gx2 = (NN + 31)/32;   // 1563
  // layer-0 GEMM1 (subsequent layers' GEMM1 are fused into k_g2's tail)
  k_g1<<<dim3(gx2,1,1), 256, 0, stream>>>(h, Bt1, bias1, Ua, Ub);
  for (int i = 0; i < 4; i++){
    k_agg<<<(NN + 11)/12, 256, 0, stream>>>(Ua, Ub, rowptr, colidx, agg);
    const bf16* nBt1   = (i < 3) ? (Bt1 + (i+1)*15360) : nullptr;
    const float* nb1   = (i < 3) ? (bias1 + (i+1)*160) : bias1;
    k_g2<<<dim3(gx2,1,1), 256, 0, stream>>>(
        h, agg, Bt2 + i*99840, bias2 + i*80, scf, invf, h,
        nBt1, nb1, Ua, Ub);
  }

  k_poolmlp<<<NGR, 128, 0, stream>>>(h, batch, mlpW, mlpb, flag, d_out);
}

// Round 13
// 520.278 us; speedup vs baseline: 1.3962x; 1.0082x over previous
//
#include <hip/hip_runtime.h>
#include <hip/hip_bf16.h>

#define NN 50000
#define NE 800000
#define FD 80
#define NGR 1024
#define NF 9

// bucketed CSR sort (atomic-free counting sort)
#define BSH 6
#define NBUCK ((NN + 63) >> 6)     // 782 node-buckets of 64
#define CSH 12
#define NCH ((NE + 4095) >> 12)    // 196 edge-chunks of 4096
#define BCAP 2048

using bf16 = __hip_bfloat16;
typedef __attribute__((ext_vector_type(8))) short bf16x8;
typedef __attribute__((ext_vector_type(4))) float f32x4;

static __device__ __forceinline__ float b2f(bf16 v){ return __bfloat162float(v); }
static __device__ __forceinline__ bf16 f2b(float v){ return __float2bfloat16(v); }
static __device__ __forceinline__ float rdw(const void* p, int i, int fl){
  return fl ? ((const float*)p)[i] : b2f(((const bf16*)p)[i]);
}
static __device__ __forceinline__ unsigned pk(float a, float b){
  bf16 x = f2b(a), y = f2b(b);
  return (unsigned)*(unsigned short*)&x | ((unsigned)*(unsigned short*)&y << 16);
}
// 8B-granule LDS access (strides are 8B- but not 16B-aligned)
static __device__ __forceinline__ bf16x8 ldsld8(const short* p){
  union { bf16x8 v; uint2 u[2]; } r;
  r.u[0] = *(const uint2*)(p);
  r.u[1] = *(const uint2*)(p + 4);
  return r.v;
}
static __device__ __forceinline__ void ldsst16(short* p, uint4 v){
  *(uint2*)(p)     = make_uint2(v.x, v.y);
  *(uint2*)(p + 4) = make_uint2(v.z, v.w);
}

// ------------------------------------------------------------------ utility
__global__ void k_zero(int* __restrict__ p, int n){
  int t = blockIdx.x*256 + threadIdx.x;
  if (t < n) p[t] = 0;
}

__global__ void k_probe(const void* __restrict__ emb, int* __restrict__ flag){
  int t = blockIdx.x*256 + threadIdx.x;
  float v = b2f(((const bf16*)emb)[t]);
  if (!(fabsf(v) < 1e4f)) atomicOr(flag, 1);
}

// ------------------------------------------------------------------ fused weight prep
// Bt1 in K-step-major FRAGMENT-TILED layout: element (c,k) at
// ks*160*32 + c*32 + (k&31) -> one wave's MFMA B-frag load is a contiguous
// 1KB segment (direct-global, no LDS staging).
__global__ __launch_bounds__(256) void k_prep_all(
    const void* __restrict__ preW, const void* __restrict__ preb,
    const void* __restrict__ postW, const void* __restrict__ postb,
    const void* __restrict__ linW, const void* __restrict__ linb,
    const void* __restrict__ bng, const void* __restrict__ bnb,
    const void* __restrict__ bnm, const void* __restrict__ bnv,
    const int* __restrict__ flag,
    bf16* __restrict__ pwb, bf16* __restrict__ Btl, bf16* __restrict__ Bt1,
    float* __restrict__ bias1, float* __restrict__ bias2)
{
  int fl = flag[0];
  int b = blockIdx.x;
  if (b < 1300){
    int t = b*256 + threadIdx.x;
    pwb[t] = f2b(rdw(postW, t, fl));
  } else if (b < 1420){
    int t = (b - 1300)*256 + threadIdx.x;
    int j = t % 96, c = (t/96) % 80, i = t/(96*80);
    float v = 0.f;
    if (j < 80){
      float gs = rdw(bng, i*80 + c, fl) * rsqrtf(rdw(bnv, i*80 + c, fl) + 1e-5f);
      v = rdw(linW, i*6400 + j*80 + c, fl) * gs;
    }
    Btl[t] = f2b(v);
  } else if (b < 1660){
    int t = (b - 1420)*256 + threadIdx.x;
    int k = t % 96, c = (t/96) % 160, i = t/(96*160);
    float v = 0.f;
    if (k < 80)
      v = (c < 80) ? rdw(preW, (i*160 + k)*80 + c, fl)
                   : rdw(preW, (i*160 + 80 + k)*80 + (c - 80), fl);
    int of = ((k >> 5)*160 + c)*32 + (k & 31);
    Bt1[i*15360 + of] = f2b(v);
    if (k == 0) bias1[i*160 + c] = (c < 80) ? rdw(preb, i*80 + c, fl) : 0.f;
  } else {
    int t = (b - 1660)*256 + threadIdx.x;
    if (t >= 4*80) return;
    int i = t / 80, f = t - i*80;
    float s = 0.f;
    for (int j = 0; j < 80; j++)
      s += rdw(postb, i*80 + j, fl) * rdw(linW, (i*80 + j)*80 + f, fl);
    s += rdw(linb, t, fl);
    float gs = rdw(bng, t, fl) * rsqrtf(rdw(bnv, t, fl) + 1e-5f);
    bias2[t] = (s - rdw(bnm, t, fl)) * gs + rdw(bnb, t, fl);
  }
}

// Bt2 in fragment-tiled layout: element (c,k) at ks*240*32 + c*32 + (k&31).
__global__ void k_prep_Bt2(const float* __restrict__ Wf, bf16* __restrict__ Bt2){
  int t = blockIdx.x*256 + threadIdx.x;
  if (t >= 4*240*416) return;
  int k = t % 416;
  int c = (t/416) % 240;
  int i = t/(416*240);
  float v = 0.f;
  if (k < 400){
    int blk = c/80, f = c - blk*80;
    if (blk == 0) v = Wf[(i*1040 + k)*80 + f];
    else if (k >= 80){
      int row = (blk == 1 ? 400 : 720) + (k - 80);
      v = Wf[(i*1040 + row)*80 + f];
    }
  }
  int of = (k >> 5)*7680 + c*32 + (k & 31);
  Bt2[i*99840 + of] = f2b(v);
}

// ------------------------------------------------------------------ graph prep
__global__ void k_atom(const int* __restrict__ x, const void* __restrict__ emb,
                       const int* __restrict__ flag, float* __restrict__ h){
  int fl = flag[0];
  int gid = blockIdx.x*256 + threadIdx.x;
  if (gid >= NN*10) return;
  int n = gid / 10, fb = gid - n*10;
  int f0 = fb*8;
  int xr[NF];
  #pragma unroll
  for (int c = 0; c < NF; c++) xr[c] = x[n*NF + c];
  float s[8] = {0.f,0.f,0.f,0.f,0.f,0.f,0.f,0.f};
  if (fl){
    #pragma unroll
    for (int c = 0; c < NF; c++){
      const float* ep = (const float*)emb + (c*119 + xr[c])*80 + f0;
      float4 a = *(const float4*)ep, b = *(const float4*)(ep + 4);
      s[0]+=a.x; s[1]+=a.y; s[2]+=a.z; s[3]+=a.w;
      s[4]+=b.x; s[5]+=b.y; s[6]+=b.z; s[7]+=b.w;
    }
  } else {
    #pragma unroll
    for (int c = 0; c < NF; c++){
      const bf16* ep = (const bf16*)emb + (c*119 + xr[c])*80 + f0;
      uint4 u = *(const uint4*)ep;
      s[0]+=__uint_as_float(u.x<<16); s[1]+=__uint_as_float(u.x&0xffff0000u);
      s[2]+=__uint_as_float(u.y<<16); s[3]+=__uint_as_float(u.y&0xffff0000u);
      s[4]+=__uint_as_float(u.z<<16); s[5]+=__uint_as_float(u.z&0xffff0000u);
      s[6]+=__uint_as_float(u.w<<16); s[7]+=__uint_as_float(u.w&0xffff0000u);
    }
  }
  float* hp = h + n*80 + f0;
  *(float4*)hp       = make_float4(s[0],s[1],s[2],s[3]);
  *(float4*)(hp + 4) = make_float4(s[4],s[5],s[6],s[7]);
}

// ---- atomic-free CSR build: hist -> cscan -> bscan -> place -> csr ----

__global__ __launch_bounds__(256) void k_hist(const int* __restrict__ ei,
                                              int* __restrict__ chunkcnt){
  __shared__ int hist[NBUCK];
  int c = blockIdx.x, t = threadIdx.x;
  for (int i = t; i < NBUCK; i += 256) hist[i] = 0;
  __syncthreads();
  #pragma unroll
  for (int j = 0; j < 16; j++){
    int e = (c << CSH) + j*256 + t;
    if (e < NE) atomicAdd(&hist[ei[NE + e] >> BSH], 1);
  }
  __syncthreads();
  for (int i = t; i < NBUCK; i += 256) chunkcnt[c*NBUCK + i] = hist[i];
}

__global__ __launch_bounds__(256) void k_cscan(int* __restrict__ chunkcnt,
                                               int* __restrict__ btotal){
  __shared__ int buf[256];
  int b = blockIdx.x, t = threadIdx.x;
  int v[4]; int s = 0;
  #pragma unroll
  for (int j = 0; j < 4; j++){
    int c = t*4 + j;
    v[j] = (c < NCH) ? chunkcnt[c*NBUCK + b] : 0;
    s += v[j];
  }
  buf[t] = s;
  __syncthreads();
  for (int off = 1; off < 256; off <<= 1){
    int xv = (t >= off) ? buf[t - off] : 0;
    __syncthreads();
    buf[t] += xv;
    __syncthreads();
  }
  int excl = buf[t] - s;
  #pragma unroll
  for (int j = 0; j < 4; j++){
    int c = t*4 + j;
    if (c < NCH){ chunkcnt[c*NBUCK + b] = excl; excl += v[j]; }
  }
  if (t == 255) btotal[b] = buf[255];
}

__global__ __launch_bounds__(256) void k_bscan(const int* __restrict__ btotal,
                                               int* __restrict__ bbase){
  __shared__ int buf[256];
  int t = threadIdx.x;
  int v[4]; int s = 0;
  #pragma unroll
  for (int j = 0; j < 4; j++){
    int c = t*4 + j;
    v[j] = (c < NBUCK) ? btotal[c] : 0;
    s += v[j];
  }
  buf[t] = s;
  __syncthreads();
  for (int off = 1; off < 256; off <<= 1){
    int xv = (t >= off) ? buf[t - off] : 0;
    __syncthreads();
    buf[t] += xv;
    __syncthreads();
  }
  int excl = buf[t] - s;
  #pragma unroll
  for (int j = 0; j < 4; j++){
    int c = t*4 + j;
    if (c < NBUCK){ bbase[c] = excl; excl += v[j]; }
  }
  if (t == 255) bbase[NBUCK] = buf[255];
}

__global__ __launch_bounds__(256) void k_place(const int* __restrict__ ei,
                        const int* __restrict__ chunkcnt, const int* __restrict__ bbase,
                        int* __restrict__ staging){
  __shared__ int basep[NBUCK];
  __shared__ int cur[NBUCK];
  int c = blockIdx.x, t = threadIdx.x;
  for (int i = t; i < NBUCK; i += 256){
    basep[i] = chunkcnt[c*NBUCK + i] + bbase[i];
    cur[i] = 0;
  }
  __syncthreads();
  #pragma unroll
  for (int j = 0; j < 16; j++){
    int e = (c << CSH) + j*256 + t;
    if (e < NE){
      int d = ei[NE + e], s = ei[e];
      int b = d >> BSH;
      int r = atomicAdd(&cur[b], 1);
      staging[basep[b] + r] = (s << BSH) | (d & 63);
    }
  }
}

__global__ __launch_bounds__(256) void k_csr(const int* __restrict__ staging,
                        const int* __restrict__ bbase, const void* __restrict__ avgp,
                        const int* __restrict__ flag, int* __restrict__ rowptr,
                        float* __restrict__ scf, float* __restrict__ invf,
                        int* __restrict__ colidx){
  __shared__ int lcnt[64], lrp[64], lcur[64];
  __shared__ int colbuf[BCAP];
  int b = blockIdx.x, t = threadIdx.x;
  int base = bbase[b];
  int cnt  = bbase[b+1] - base;
  if (t < 64){ lcnt[t] = 0; lcur[t] = 0; }
  __syncthreads();
  for (int i = t; i < cnt; i += 256)
    atomicAdd(&lcnt[staging[base + i] & 63], 1);
  __syncthreads();
  if (t < 64) lrp[t] = lcnt[t];
  __syncthreads();
  for (int off = 1; off < 64; off <<= 1){
    int xv = (t < 64 && t >= off) ? lrp[t - off] : 0;
    __syncthreads();
    if (t < 64) lrp[t] += xv;
    __syncthreads();
  }
  int n0 = b << BSH;
  if (t < 64){
    int ex = lrp[t] - lcnt[t];
    lrp[t] = ex;
    int n = n0 + t;
    if (n < NN){
      rowptr[n] = base + ex;
      float degc = (float)(lcnt[t] > 0 ? lcnt[t] : 1);
      float logd = logf(degc + 1.f);
      float avg = rdw(avgp, 0, flag[0]);
      scf[n] = logd / avg;
      invf[n] = avg / logd;
    }
  }
  if (b == 0 && t == 0) rowptr[NN] = NE;
  __syncthreads();
  if (cnt <= BCAP){
    for (int i = t; i < cnt; i += 256){
      int v = staging[base + i];
      int l = v & 63;
      int pos = lrp[l] + atomicAdd(&lcur[l], 1);
      colbuf[pos] = v >> BSH;
    }
    __syncthreads();
    for (int i = t; i < cnt; i += 256)
      colidx[base + i] = colbuf[i];
  } else {
    for (int i = t; i < cnt; i += 256){
      int v = staging[base + i];
      int l = v & 63;
      int pos = lrp[l] + atomicAdd(&lcur[l], 1);
      colidx[base + pos] = v >> BSH;
    }
  }
}

// ------------------------------------------------------------------ MFMA GEMM (r4 structure; Wf only)
template<int AF32, int OUTMODE, int K_, int AST>
__global__ __launch_bounds__(256) void k_mgemm(
    const void* __restrict__ A1p, int s1, int KA,
    const bf16* __restrict__ A2, int s2, int KB,
    const bf16* __restrict__ Btp, int Bts, int Ncols,
    const float* __restrict__ bias,
    void* __restrict__ Cbase, void* __restrict__ Cp2, int Cstride, int M,
    int lA1b, int lBtb, int lCb)
{
  const void* A1 = (const char*)A1p + (size_t)blockIdx.z*lA1b;
  const bf16* Bt = (const bf16*)((const char*)Btp + (size_t)blockIdx.z*lBtb);
  void* Cp = (char*)Cbase + (size_t)blockIdx.z*lCb;

  constexpr int NKT = K_ / 32;
  __shared__ short As[64*AST];
  __shared__ short Bs[256*44];

  const int tid = threadIdx.x;
  const int row0 = blockIdx.x * 64;
  const int wave = tid >> 6, lane = tid & 63;
  const int wc = wave * 64;
  const int m16 = lane & 15, q = lane >> 4;

  const int ra = tid >> 2, ka = (tid & 3) * 8;
  const int cb = tid >> 2, kb = (tid & 3) * 8;

  f32x4 acc[4][4] = {};
  uint4 pb[4];

#define LOADB(k0_) { int kgb = (k0_) + kb;                                     \
    _Pragma("unroll")                                                          \
    for (int j = 0; j < 4; j++){                                               \
      int col = cb + j*64;                                                     \
      pb[j].x = pb[j].y = pb[j].z = pb[j].w = 0u;                              \
      if (col < Ncols) pb[j] = *(const uint4*)(Bt + col*Bts + kgb);            \
    } }

  LOADB(0);

  {
    const int grow = row0 + ra;
    uint4 tA[NKT];
    #pragma unroll
    for (int c = 0; c < NKT; c++){
      int kg = c*32 + ka;
      uint4 pa; pa.x = pa.y = pa.z = pa.w = 0u;
      if (grow < M){
        if (kg < KA){
          if (AF32){
            const float* ap = (const float*)A1 + grow*s1 + kg;
            float4 f0 = *(const float4*)ap;
            float4 f1 = *(const float4*)(ap + 4);
            pa.x = pk(f0.x, f0.y); pa.y = pk(f0.z, f0.w);
            pa.z = pk(f1.x, f1.y); pa.w = pk(f1.z, f1.w);
          } else {
            pa = *(const uint4*)((const bf16*)A1 + grow*s1 + kg);
          }
        } else if (kg - KA < KB){
          pa = *(const uint4*)(A2 + grow*s2 + (kg - KA));
        }
      }
      tA[c] = pa;
    }
    #pragma unroll
    for (int c = 0; c < NKT; c++)
      ldsst16(&As[ra*AST + c*32 + ka], tA[c]);
  }
  __syncthreads();

  #pragma unroll
  for (int ks = 0; ks < NKT; ks++){
    #pragma unroll
    for (int j = 0; j < 4; j++)
      ldsst16(&Bs[(cb + j*64)*44 + kb], pb[j]);
    __syncthreads();

    if (ks + 1 < NKT) LOADB((ks + 1)*32);

    bf16x8 af[4], bfv[4];
    #pragma unroll
    for (int rt = 0; rt < 4; rt++)
      af[rt] = ldsld8(&As[(rt*16 + m16)*AST + ks*32 + q*8]);
    #pragma unroll
    for (int ct = 0; ct < 4; ct++)
      bfv[ct] = ldsld8(&Bs[(wc + ct*16 + m16)*44 + q*8]);
    #pragma unroll
    for (int rt = 0; rt < 4; rt++)
      #pragma unroll
      for (int ct = 0; ct < 4; ct++)
        acc[rt][ct] = __builtin_amdgcn_mfma_f32_16x16x32_bf16(af[rt], bfv[ct], acc[rt][ct], 0, 0, 0);
    __syncthreads();
  }
#undef LOADB

  #pragma unroll
  for (int rt = 0; rt < 4; rt++){
    #pragma unroll
    for (int rr = 0; rr < 4; rr++){
      int row = row0 + rt*16 + q*4 + rr;
      if (row >= M) continue;
      #pragma unroll
      for (int ct = 0; ct < 4; ct++){
        int col = wc + ct*16 + m16;
        if (col >= Ncols) continue;
        float v = acc[rt][ct][rr] + (bias ? bias[col] : 0.f);
        if (OUTMODE == 1) ((float*)Cp)[row*Cstride + col] = v;
        else {
          if (col < 80) ((bf16*)Cp )[row*80 + col]      = f2b(v);
          else          ((bf16*)Cp2)[row*80 + col - 80] = f2b(v);
        }
      }
    }
  }
}

// ------------------------------------------------------------------ layer-0 GEMM1 (direct tiled-B, barrier-free)
__global__ __launch_bounds__(256) void k_g1(
    const float* __restrict__ h, const bf16* __restrict__ Bt1t,
    const float* __restrict__ bias1v,
    bf16* __restrict__ Ua, bf16* __restrict__ Ub)
{
  __shared__ short hA[32*100];   // 6,400 B
  const int tid = threadIdx.x;
  const int row0 = blockIdx.x * 32;
  const int wave = tid >> 6, lane = tid & 63;
  const int wc = wave * 64;
  const int m16 = lane & 15, q = lane >> 4;
  const int ra = tid >> 3, ka0 = (tid & 7) * 8;

  // stage h rows (f32->bf16); zero pad k in [80,96)
  {
    int grow = row0 + ra;
    #pragma unroll
    for (int c = 0; c < 2; c++){
      int kg = ka0 + c*64;
      if (kg < 96){
        uint4 pa; pa.x = pa.y = pa.z = pa.w = 0u;
        if (kg < 80 && grow < NN){
          const float* ap = h + grow*80 + kg;
          float4 f0 = *(const float4*)ap, f1 = *(const float4*)(ap + 4);
          pa.x = pk(f0.x, f0.y); pa.y = pk(f0.z, f0.w);
          pa.z = pk(f1.x, f1.y); pa.w = pk(f1.z, f1.w);
        }
        ldsst16(&hA[ra*100 + kg], pa);
      }
    }
  }
  __syncthreads();

  const bf16* bp1[4];
  #pragma unroll
  for (int ct = 0; ct < 4; ct++){
    int col = wc + ct*16 + m16;
    if (col >= 160) col = 0;
    bp1[ct] = Bt1t + col*32 + q*8;
  }
  f32x4 acc[2][4] = {};
  #pragma unroll
  for (int ks = 0; ks < 3; ks++){
    bf16x8 bfv[4], af[2];
    #pragma unroll
    for (int ct = 0; ct < 4; ct++)
      bfv[ct] = *(const bf16x8*)(bp1[ct] + ks*5120);
    #pragma unroll
    for (int rt = 0; rt < 2; rt++)
      af[rt] = ldsld8(&hA[(rt*16 + m16)*100 + ks*32 + q*8]);
    #pragma unroll
    for (int rt = 0; rt < 2; rt++)
      #pragma unroll
      for (int ct = 0; ct < 4; ct++)
        acc[rt][ct] = __builtin_amdgcn_mfma_f32_16x16x32_bf16(af[rt], bfv[ct], acc[rt][ct], 0, 0, 0);
  }
  #pragma unroll
  for (int rt = 0; rt < 2; rt++){
    #pragma unroll
    for (int rr = 0; rr < 4; rr++){
      int row = row0 + rt*16 + q*4 + rr;
      if (row >= NN) continue;
      #pragma unroll
      for (int ct = 0; ct < 4; ct++){
        int col = wc + ct*16 + m16;
        if (col >= 160) continue;
        float v = acc[rt][ct][rr] + bias1v[col];
        if (col < 80) Ua[row*80 + col]      = f2b(v);
        else          Ub[row*80 + col - 80] = f2b(v);
      }
    }
  }
}

// ------------------------------------------------------------------ GEMM2 + fused next-layer GEMM1
// 32-row tile, direct tiled-B, barrier-free K-loop, EXPLICIT DEPTH-2 B
// PREFETCH (round-12 evidence: VGPR=52 -> compiler pipelined B loads at
// depth ~1; each step's MFMA eats L2 latency. Two statically-named buffers,
// full unroll folds ks&1 -> registers).
__global__ __launch_bounds__(256) void k_g2(
    const float* __restrict__ h, const bf16* __restrict__ agg,
    const bf16* __restrict__ Bt, const float* __restrict__ bias2v,
    const float* __restrict__ scf, const float* __restrict__ invf,
    float* __restrict__ hp,
    const bf16* __restrict__ Bt1n, const float* __restrict__ bias1n,
    bf16* __restrict__ Ua, bf16* __restrict__ Ub)
{
  constexpr int AST = 420, NKT = 13;
  __shared__ short As[32*AST];   // 26,880 B
  bf16* eL = (bf16*)As;                 // epilogue staging 32x248 (15,872 B)
  bf16* hA = (bf16*)(As + 8192);        // h_new panel 32x100 (bytes 16,384..22,784)

  const int tid = threadIdx.x;
  const int row0 = blockIdx.x * 32;
  const int wave = tid >> 6, lane = tid & 63;
  const int wc = wave * 64;
  const int m16 = lane & 15, q = lane >> 4;
  const int ra = tid >> 3;           // 32 rows, 8 threads/row
  const int ka0 = (tid & 7) * 8;     // chunk start; stride 64 shorts

  // ---- stage A panel: k<80 from h (f32->bf16), 80<=k<400 from agg, else 0
  {
    const int grow = row0 + ra;
    uint4 tA[7];
    #pragma unroll
    for (int c = 0; c < 7; c++){
      int kg = ka0 + c*64;
      uint4 pa; pa.x = pa.y = pa.z = pa.w = 0u;
      if (kg < 416 && grow < NN){
        if (kg < 80){
          const float* ap = h + grow*80 + kg;
          float4 f0 = *(const float4*)ap;
          float4 f1 = *(const float4*)(ap + 4);
          pa.x = pk(f0.x, f0.y); pa.y = pk(f0.z, f0.w);
          pa.z = pk(f1.x, f1.y); pa.w = pk(f1.z, f1.w);
        } else if (kg < 400){
          pa = *(const uint4*)(agg + grow*320 + (kg - 80));
        }
      }
      tA[c] = pa;
    }
    #pragma unroll
    for (int c = 0; c < 7; c++){
      int kg = ka0 + c*64;
      if (kg < 416) ldsst16(&As[ra*AST + kg], tA[c]);
    }
  }

  // ---- per-lane tiled-B base pointers (OOB cols clamped; their acc unused)
  const bf16* bp[4];
  #pragma unroll
  for (int ct = 0; ct < 4; ct++){
    int col = wc + ct*16 + m16;
    if (col >= 240) col = 0;
    bp[ct] = Bt + col*32 + q*8;
  }
  __syncthreads();   // A panel ready

  f32x4 acc[2][4] = {};

  // ---- barrier-free K loop with explicit depth-2 B prefetch
  bf16x8 b0[4], b1[4];
  #pragma unroll
  for (int ct = 0; ct < 4; ct++) b0[ct] = *(const bf16x8*)(bp[ct]);
  #pragma unroll
  for (int ct = 0; ct < 4; ct++) b1[ct] = *(const bf16x8*)(bp[ct] + 7680);
  #pragma unroll
  for (int ks = 0; ks < NKT; ks++){
    bf16x8 bfv[4];
    #pragma unroll
    for (int ct = 0; ct < 4; ct++)
      bfv[ct] = (ks & 1) ? b1[ct] : b0[ct];
    if (ks + 2 < NKT){
      #pragma unroll
      for (int ct = 0; ct < 4; ct++){
        bf16x8 v = *(const bf16x8*)(bp[ct] + (ks + 2)*7680);
        if (ks & 1) b1[ct] = v; else b0[ct] = v;
      }
    }
    bf16x8 af[2];
    #pragma unroll
    for (int rt = 0; rt < 2; rt++)
      af[rt] = ldsld8(&As[(rt*16 + m16)*AST + ks*32 + q*8]);
    #pragma unroll
    for (int rt = 0; rt < 2; rt++)
      #pragma unroll
      for (int ct = 0; ct < 4; ct++)
        acc[rt][ct] = __builtin_amdgcn_mfma_f32_16x16x32_bf16(af[rt], bfv[ct], acc[rt][ct], 0, 0, 0);
  }
  __syncthreads();   // all waves done reading As before eL overwrite

  // ---- epilogue: stage P|Q|R in eL
  #pragma unroll
  for (int rt = 0; rt < 2; rt++){
    #pragma unroll
    for (int ct = 0; ct < 4; ct++){
      int col = wc + ct*16 + m16;
      if (col >= 240) continue;
      #pragma unroll
      for (int rr = 0; rr < 4; rr++){
        int r = rt*16 + q*4 + rr;
        eL[r*248 + col] = f2b(acc[rt][ct][rr]);
      }
    }
  }
  __syncthreads();

  // ---- combine -> h_new; write global f32 + LDS bf16 panel
  #pragma unroll
  for (int i = 0; i < 10; i++){
    int idx = tid + i*256;
    int r = idx / 80, c = idx - r*80;
    int row = row0 + r;
    if (row < NN){
      float P = b2f(eL[r*248 + c]);
      float Q = b2f(eL[r*248 + 80 + c]);
      float R = b2f(eL[r*248 + 160 + c]);
      float o = P + scf[row]*Q + invf[row]*R + bias2v[c];
      float hn = hp[row*80 + c] + fmaxf(o, 0.f);
      hp[row*80 + c] = hn;
      if (Bt1n) hA[r*100 + c] = f2b(hn);
    } else if (Bt1n && idx < 32*80){
      hA[r*100 + c] = f2b(0.f);   // tail rows: defined values for mini-GEMM
    }
  }
  if (Bt1n && tid < 128){
    // zero pad k in [80,96)
    int r = tid >> 2, off = 80 + (tid & 3)*4;
    *(uint2*)&hA[r*100 + off] = make_uint2(0u, 0u);
  }
  __syncthreads();

  // ---- mini-GEMM: U = h_new @ Bt1[next] (tiled-B, barrier-free)
  if (Bt1n){
    const bf16* bp1[4];
    #pragma unroll
    for (int ct = 0; ct < 4; ct++){
      int col = wc + ct*16 + m16;
      if (col >= 160) col = 0;
      bp1[ct] = Bt1n + col*32 + q*8;
    }
    f32x4 acc2[2][4] = {};
    #pragma unroll
    for (int ks = 0; ks < 3; ks++){
      bf16x8 bfv[4], af[2];
      #pragma unroll
      for (int ct = 0; ct < 4; ct++)
        bfv[ct] = *(const bf16x8*)(bp1[ct] + ks*5120);
      #pragma unroll
      for (int rt = 0; rt < 2; rt++)
        af[rt] = ldsld8((const short*)hA + (rt*16 + m16)*100 + ks*32 + q*8);
      #pragma unroll
      for (int rt = 0; rt < 2; rt++)
        #pragma unroll
        for (int ct = 0; ct < 4; ct++)
          acc2[rt][ct] = __builtin_amdgcn_mfma_f32_16x16x32_bf16(af[rt], bfv[ct], acc2[rt][ct], 0, 0, 0);
    }
    #pragma unroll
    for (int rt = 0; rt < 2; rt++){
      #pragma unroll
      for (int rr = 0; rr < 4; rr++){
        int row = row0 + rt*16 + q*4 + rr;
        if (row >= NN) continue;
        #pragma unroll
        for (int ct = 0; ct < 4; ct++){
          int col = wc + ct*16 + m16;
          if (col >= 160) continue;
          float v = acc2[rt][ct][rr] + bias1n[col];
          if (col < 80) Ua[row*80 + col]      = f2b(v);
          else          Ub[row*80 + col - 80] = f2b(v);
        }
      }
    }
  }
}

// ------------------------------------------------------------------ aggregation
// 3 nodes/wave: lane/20 = node slot, (lane%20)*4 = feature offset.
// Batch 16 (mean degree): one batch covers a typical node's whole edge list
// -> 16 gathers in flight per lane (was 8), half the latency-exposed
// batch boundaries.
__global__ __launch_bounds__(256) void k_agg(const bf16* __restrict__ Ua,
                      const bf16* __restrict__ Ub,
                      const int* __restrict__ rowptr,
                      const int* __restrict__ colidx, bf16* __restrict__ agg)
{
  int lane = threadIdx.x & 63;
  int slot = lane / 20;
  int n = blockIdx.x*12 + (threadIdx.x >> 6)*3 + slot;
  if (slot >= 3 || n >= NN) return;
  int fo = (lane - slot*20) * 4;
  int rs = rowptr[n], re = rowptr[n+1];
  int deg = re - rs;

  float a[4];
  {
    uint2 ua = *(const uint2*)(Ua + n*80 + fo);
    a[0] = __uint_as_float(ua.x << 16);
    a[1] = __uint_as_float(ua.x & 0xffff0000u);
    a[2] = __uint_as_float(ua.y << 16);
    a[3] = __uint_as_float(ua.y & 0xffff0000u);
  }
  float sb[4] = {0.f,0.f,0.f,0.f}, sq[4] = {0.f,0.f,0.f,0.f};
  float mn[4] = {1e30f,1e30f,1e30f,1e30f}, mx[4] = {-1e30f,-1e30f,-1e30f,-1e30f};

#define ACC2(w, o) { \
    float b0 = __uint_as_float((w) << 16); \
    float b1 = __uint_as_float((w) & 0xffff0000u); \
    sb[o] += b0; sq[o] += b0*b0; mn[o] = fminf(mn[o],b0); mx[o] = fmaxf(mx[o],b0); \
    sb[o+1] += b1; sq[o+1] += b1*b1; mn[o+1] = fminf(mn[o+1],b1); mx[o+1] = fmaxf(mx[o+1],b1); }

  for (int e = rs; e < re; e += 16){
    int cnt = re - e; if (cnt > 16) cnt = 16;
    int s[16];
    #pragma unroll
    for (int j = 0; j < 16; j++) s[j] = (j < cnt) ? colidx[e + j] : s[0];
    uint2 u[16];
    #pragma unroll
    for (int j = 0; j < 16; j++) u[j] = *(const uint2*)(Ub + s[j]*80 + fo);
    #pragma unroll
    for (int j = 0; j < 16; j++){
      if (j < cnt){ ACC2(u[j].x, 0); ACC2(u[j].y, 2); }
    }
  }
#undef ACC2

  float degc = (float)(deg > 0 ? deg : 1);
  float inv = 1.f/degc;
  float dm = (float)deg;
  float mean0, mean1, v0, v1, sd0, sd1, lo0, lo1, hi0, hi1;

  mean0 = (dm*a[0] + sb[0])*inv; mean1 = (dm*a[1] + sb[1])*inv;
  v0 = (dm*a[0]*a[0] + 2.f*a[0]*sb[0] + sq[0])*inv - mean0*mean0;
  v1 = (dm*a[1]*a[1] + 2.f*a[1]*sb[1] + sq[1])*inv - mean1*mean1;
  sd0 = sqrtf(fmaxf(v0,0.f)+1e-5f); sd1 = sqrtf(fmaxf(v1,0.f)+1e-5f);
  lo0 = deg>0 ? a[0]+mn[0] : 0.f; lo1 = deg>0 ? a[1]+mn[1] : 0.f;
  hi0 = deg>0 ? a[0]+mx[0] : 0.f; hi1 = deg>0 ? a[1]+mx[1] : 0.f;
  unsigned o0 = pk(mean0, mean1);
  unsigned l0 = pk(lo0, lo1), h0 = pk(hi0, hi1), t0 = pk(sd0, sd1);

  mean0 = (dm*a[2] + sb[2])*inv; mean1 = (dm*a[3] + sb[3])*inv;
  v0 = (dm*a[2]*a[2] + 2.f*a[2]*sb[2] + sq[2])*inv - mean0*mean0;
  v1 = (dm*a[3]*a[3] + 2.f*a[3]*sb[3] + sq[3])*inv - mean1*mean1;
  sd0 = sqrtf(fmaxf(v0,0.f)+1e-5f); sd1 = sqrtf(fmaxf(v1,0.f)+1e-5f);
  lo0 = deg>0 ? a[2]+mn[2] : 0.f; lo1 = deg>0 ? a[3]+mn[3] : 0.f;
  hi0 = deg>0 ? a[2]+mx[2] : 0.f; hi1 = deg>0 ? a[3]+mx[3] : 0.f;
  unsigned o1 = pk(mean0, mean1);
  unsigned l1 = pk(lo0, lo1), h1 = pk(hi0, hi1), t1 = pk(sd0, sd1);

  bf16* ag = agg + n*320 + fo;
  *(uint2*)(ag)       = make_uint2(o0, o1);
  *(uint2*)(ag + 80)  = make_uint2(l0, l1);
  *(uint2*)(ag + 160) = make_uint2(h0, h1);
  *(uint2*)(ag + 240) = make_uint2(t0, t1);
}

// ------------------------------------------------------------------ fused mean-pool + head
__global__ __launch_bounds__(128) void k_poolmlp(const float* __restrict__ h,
                        const int* __restrict__ batch,
                        const void* __restrict__ mlpW, const void* __restrict__ mlpb,
                        const int* __restrict__ flag, void* __restrict__ outp){
  __shared__ float sred[128];
  __shared__ int sb[2];
  int g = blockIdx.x;
  int t = threadIdx.x;
  if (t < 2){
    int target = g + t;
    int lo = 0, hi = NN;
    while (lo < hi){ int mid = (lo + hi) >> 1; if (batch[mid] < target) lo = mid + 1; else hi = mid; }
    sb[t] = lo;
  }
  __syncthreads();
  int lo = sb[0], hi = sb[1];
  float s = 0.f;
  if (t < 80)
    for (int n = lo; n < hi; n++) s += h[n*80 + t];
  int fl = flag[0];
  float wv = (t < 80) ? rdw(mlpW, t, fl) : 0.f;
  sred[t] = s * wv;
  __syncthreads();
  for (int off = 64; off > 0; off >>= 1){
    if (t < off) sred[t] += sred[t + off];
    __syncthreads();
  }
  if (t == 0){
    float cnt = (float)(hi - lo); if (cnt < 1.f) cnt = 1.f;
    float r = sred[0]/cnt + rdw(mlpb, 0, fl);
    if (fl) ((float*)outp)[g] = r;
    else    ((bf16*)outp)[g] = f2b(r);
  }
}

// ------------------------------------------------------------------ launch
extern "C" void kernel_launch(void* const* d_in, const int* in_sizes, int n_in,
                              void* d_out, int out_size, void* d_ws, size_t ws_size,
                              hipStream_t stream)
{
  const int*  x     = (const int*) d_in[0];
  const int*  ei    = (const int*) d_in[1];
  const int*  batch = (const int*) d_in[2];
  const void* avgp  = d_in[3];
  const void* aemb  = d_in[4];
  const void* preW  = d_in[5];
  const void* preb  = d_in[6];
  const void* postW = d_in[7];
  const void* postb = d_in[8];
  const void* linW  = d_in[9];
  const void* linb  = d_in[10];
  const void* bng   = d_in[11];
  const void* bnb   = d_in[12];
  const void* bnm   = d_in[13];
  const void* bnv   = d_in[14];
  const void* mlpW  = d_in[15];
  const void* mlpb  = d_in[16];

  char* w = (char*)d_ws;
  int*   flag   = (int*)  (w + 400000);       //       256  (zeroed)
  int*   rowptr = (int*)  (w + 401280);       //   200,064
  int*   colidx = (int*)  (w + 601344);       // 3,200,000
  float* scf    = (float*)(w + 3801344);      //   200,000
  float* invf   = (float*)(w + 4001344);      //   200,000
  float* bias1  = (float*)(w + 4201344);      //     2,560
  float* bias2  = (float*)(w + 4203904);      //     1,280
  bf16*  Btl    = (bf16*) (w + 4205184);      //    61,440
  bf16*  Bt1    = (bf16*) (w + 4266624);      //   122,880  (tiled layout)
  bf16*  Bt2    = (bf16*) (w + 4389504);      //   798,720  (tiled layout)
  float* h      = (float*)(w + 5188224);      // 16,000,000  f32 [N,80]
  bf16*  Ua     = (bf16*) (w + 21188224);     //  8,000,000  bf16 [N,80]
  bf16*  Ub     = (bf16*) (w + 29188224);     //  8,000,000  bf16 [N,80]
  bf16*  agg    = (bf16*) (w + 45188224);     // 32,000,000  bf16 [N,320]
  // pre-loop overlays inside the agg region:
  bf16*  pwb    = (bf16*) (w + 45188224);     //   665,600
  float* Wf     = (float*)(w + 45853824);     // 1,331,200
  int* staging  = (int*)  (w + 47185024);     // 3,200,000
  int* chunkcnt = (int*)  (w + 50385024);     //   613,088  [NCH][NBUCK]
  int* btotal   = (int*)  (w + 52831120);     //     3,128
  int* bbase    = (int*)  (w + 52834248);     //     3,136  (NBUCK+1)
  // total 77,188,224 B

  k_zero <<<1, 256, 0, stream>>>(flag, 64);
  k_probe<<<16, 256, 0, stream>>>(aemb, flag);

  // atomic-free CSR build
  k_hist <<<NCH, 256, 0, stream>>>(ei, chunkcnt);
  k_cscan<<<NBUCK, 256, 0, stream>>>(chunkcnt, btotal);
  k_bscan<<<1, 256, 0, stream>>>(btotal, bbase);
  k_place<<<NCH, 256, 0, stream>>>(ei, chunkcnt, bbase, staging);

  k_prep_all<<<1662, 256, 0, stream>>>(preW, preb, postW, postb, linW, linb,
                                       bng, bnb, bnm, bnv, flag,
                                       pwb, Btl, Bt1, bias1, bias2);

  // Wf[i] = postW[i](bf16) @ Btl[i]^T   (f32 out)
  k_mgemm<0,1,96,100><<<dim3(17,1,4), 256, 0, stream>>>(
      pwb, 80, 80, nullptr, 0, 0,
      Btl, 96, 80, nullptr, Wf, nullptr, 80, 1040,
      166400, 15360, 332800);
  k_prep_Bt2<<<(4*240*416 + 255)/256, 256, 0, stream>>>(Wf, Bt2);

  k_atom <<<(NN*10 + 255)/256, 256, 0, stream>>>(x, aemb, flag, h);

  // fused rowptr/scf/invf + counting-sorted colidx
  k_csr<<<NBUCK, 256, 0, stream>>>(staging, bbase, avgp, flag, rowptr, scf, invf, colidx);

  const int gx2 = (NN + 31)/32;   // 1563
  // layer-0 GEMM1 (subsequent layers' GEMM1 are fused into k_g2's tail)
  k_g1<<<dim3(gx2,1,1), 256, 0, stream>>>(h, Bt1, bias1, Ua, Ub);
  for (int i = 0; i < 4; i++){
    k_agg<<<(NN + 11)/12, 256, 0, stream>>>(Ua, Ub, rowptr, colidx, agg);
    const bf16* nBt1   = (i < 3) ? (Bt1 + (i+1)*15360) : nullptr;
    const float* nb1   = (i < 3) ? (bias1 + (i+1)*160) : bias1;
    k_g2<<<dim3(gx2,1,1), 256, 0, stream>>>(
        h, agg, Bt2 + i*99840, bias2 + i*80, scf, invf, h,
        nBt1, nb1, Ua, Ub);
  }

  k_poolmlp<<<NGR, 128, 0, stream>>>(h, batch, mlpW, mlpb, flag, d_out);
}